// Round 1
// baseline (1852.495 us; speedup 1.0000x reference)
//
#include <hip/hip_runtime.h>
#include <math.h>

#define HD 128
#define NGRAPH 64

__device__ __forceinline__ float4 ld4(const float* p){ return *(const float4*)p; }

// ---------------- CSR build ----------------
__global__ __launch_bounds__(256) void k_count(const int* __restrict__ dst, int* __restrict__ deg, int E){
  int e = blockIdx.x*256 + threadIdx.x;
  if (e < E) atomicAdd(&deg[dst[e]], 1);
}

__global__ __launch_bounds__(256) void k_scan1(const int* __restrict__ deg, int* __restrict__ rp,
                                               int* __restrict__ bt, int N){
  __shared__ int sm[256];
  int i = blockIdx.x*256 + threadIdx.x;
  int v = (i < N) ? deg[i] : 0;
  sm[threadIdx.x] = v;
  __syncthreads();
  for (int off = 1; off < 256; off <<= 1){
    int t = (threadIdx.x >= (unsigned)off) ? sm[threadIdx.x - off] : 0;
    __syncthreads();
    sm[threadIdx.x] += t;
    __syncthreads();
  }
  if (i < N) rp[i+1] = sm[threadIdx.x];
  if (threadIdx.x == 255) bt[blockIdx.x] = sm[255];
  if (blockIdx.x == 0 && threadIdx.x == 0) rp[0] = 0;
}

__global__ __launch_bounds__(256) void k_scan2(const int* __restrict__ bt, int* __restrict__ bo, int NB){
  __shared__ int sm[256];
  int t = threadIdx.x;
  int v = (t < NB) ? bt[t] : 0;
  sm[t] = v;
  __syncthreads();
  for (int off = 1; off < 256; off <<= 1){
    int u = (t >= (unsigned)off) ? sm[t - off] : 0;
    __syncthreads();
    sm[t] += u;
    __syncthreads();
  }
  if (t < NB) bo[t] = sm[t] - v;   // exclusive offset per block
}

__global__ __launch_bounds__(256) void k_scan3(int* __restrict__ rp, const int* __restrict__ bo, int N){
  int i = blockIdx.x*256 + threadIdx.x;
  if (i < N) rp[i+1] += bo[i >> 8];
}

__global__ __launch_bounds__(256) void k_scatter(const int* __restrict__ src, const int* __restrict__ dst,
                                                 const int* __restrict__ rp, int* __restrict__ cursor,
                                                 int* __restrict__ srcs, int E){
  int e = blockIdx.x*256 + threadIdx.x;
  if (e < E){
    int d = dst[e];
    int pos = atomicAdd(&cursor[d], 1);
    srcs[rp[d] + pos] = src[e];
  }
}

__global__ __launch_bounds__(256) void k_gcount(const int* __restrict__ batch, int* __restrict__ gcnt, int N){
  int n = blockIdx.x*256 + threadIdx.x;
  if (n < N) atomicAdd(&gcnt[batch[n]], 1);
}

// ---------------- layer 1 projection (in_dim = 1) ----------------
__global__ __launch_bounds__(256) void k_layer1(
    const float* __restrict__ X,
    const float* __restrict__ Wq1, const float* __restrict__ bq1,
    const float* __restrict__ Wk1, const float* __restrict__ bk1,
    const float* __restrict__ Wv1, const float* __restrict__ bv1,
    const float* __restrict__ Ws1, const float* __restrict__ bs1,
    float* __restrict__ q, float* __restrict__ k, float* __restrict__ v, float* __restrict__ h, int N){
  int idx = blockIdx.x*256 + threadIdx.x;
  if (idx >= N*HD) return;
  int n = idx >> 7, c = idx & 127;
  float xv = X[n];
  q[idx] = xv*Wq1[c] + bq1[c];
  k[idx] = xv*Wk1[c] + bk1[c];
  v[idx] = xv*Wv1[c] + bv1[c];
  h[idx] = xv*Ws1[c] + bs1[c];
}

// ---------------- fused QKVS GEMM: out[colgrp] = x @ W + b ----------------
// grid = (ceil(N/64), 8): blockIdx.y selects {q,k,v,h} x {cols 0-63, 64-127}
__global__ __launch_bounds__(256) void k_gemm(
    const float* __restrict__ x,
    const float* __restrict__ Wq, const float* __restrict__ Wk,
    const float* __restrict__ Wv, const float* __restrict__ Ws,
    const float* __restrict__ bq, const float* __restrict__ bk,
    const float* __restrict__ bv, const float* __restrict__ bs,
    float* __restrict__ q, float* __restrict__ k, float* __restrict__ v, float* __restrict__ h,
    int nrows){
  __shared__ float As[64*36];   // x tile [64 rows][32 k], stride 36 (16B-aligned, conflict-friendly)
  __shared__ float Bs[32*64];   // W tile [32 k][64 cols]

  int wsel = blockIdx.y >> 1;
  int c0   = (blockIdx.y & 1) * 64;
  const float* W    = (wsel==0)?Wq:(wsel==1)?Wk:(wsel==2)?Wv:Ws;
  const float* bias = (wsel==0)?bq:(wsel==1)?bk:(wsel==2)?bv:bs;
  float* out        = (wsel==0)?q :(wsel==1)?k :(wsel==2)?v :h;

  int row0 = blockIdx.x * 64;
  int tid  = threadIdx.x;
  int tx = tid & 15, ty = tid >> 4;   // tx: col/4, ty: row/4
  int r0 = ty*4, cc = tx*4;

  float acc[4][4] = {{0.f,0.f,0.f,0.f},{0.f,0.f,0.f,0.f},{0.f,0.f,0.f,0.f},{0.f,0.f,0.f,0.f}};

  for (int kc = 0; kc < 128; kc += 32){
    // stage x tile: 64 rows x 32 k = 512 float4
    for (int i = tid; i < 512; i += 256){
      int r = i >> 3;
      int kk4 = (i & 7) << 2;
      int gr = row0 + r;
      float4 val = (gr < nrows) ? ld4(x + gr*HD + kc + kk4) : make_float4(0.f,0.f,0.f,0.f);
      *(float4*)&As[r*36 + kk4] = val;
    }
    // stage W tile: 32 k x 64 cols = 512 float4
    for (int i = tid; i < 512; i += 256){
      int kk = i >> 4;
      int cc4 = (i & 15) << 2;
      *(float4*)&Bs[kk*64 + cc4] = ld4(W + (kc+kk)*HD + c0 + cc4);
    }
    __syncthreads();

    #pragma unroll
    for (int kk = 0; kk < 32; kk += 4){
      float a[4][4], b[4][4];
      #pragma unroll
      for (int i = 0; i < 4; ++i) *(float4*)a[i] = *(const float4*)&As[(r0+i)*36 + kk];
      #pragma unroll
      for (int j = 0; j < 4; ++j) *(float4*)b[j] = *(const float4*)&Bs[(kk+j)*64 + cc];
      #pragma unroll
      for (int i = 0; i < 4; ++i)
        #pragma unroll
        for (int p = 0; p < 4; ++p)
          #pragma unroll
          for (int j = 0; j < 4; ++j)
            acc[i][j] = fmaf(a[i][p], b[p][j], acc[i][j]);
    }
    __syncthreads();
  }

  #pragma unroll
  for (int i = 0; i < 4; ++i){
    int gr = row0 + r0 + i;
    if (gr < nrows){
      float4 ob;
      ob.x = acc[i][0] + bias[c0+cc+0];
      ob.y = acc[i][1] + bias[c0+cc+1];
      ob.z = acc[i][2] + bias[c0+cc+2];
      ob.w = acc[i][3] + bias[c0+cc+3];
      *(float4*)(out + gr*HD + c0 + cc) = ob;
    }
  }
}

// ---------------- attention: one wave per dst node, online softmax ----------------
__global__ __launch_bounds__(256) void k_attn(
    const float* __restrict__ q, const float* __restrict__ k, const float* __restrict__ v,
    float* __restrict__ h, const int* __restrict__ rp, const int* __restrict__ srcs, int N){
  int wave = (blockIdx.x*256 + threadIdx.x) >> 6;
  int lane = threadIdx.x & 63;
  if (wave >= N) return;
  int n = wave;
  int c0 = lane * 2;
  float2 qv = *(const float2*)(q + n*HD + c0);
  int beg = rp[n], end = rp[n+1];
  float m = -INFINITY, lsum = 0.f, a0 = 0.f, a1 = 0.f;
  for (int t = beg; t < end; ++t){
    int s = srcs[t];
    float2 kv = *(const float2*)(k + s*HD + c0);
    float2 vv = *(const float2*)(v + s*HD + c0);
    float p = qv.x*kv.x + qv.y*kv.y;
    p += __shfl_xor(p, 1);
    p += __shfl_xor(p, 2);
    p += __shfl_xor(p, 4);
    float alpha = p * 0.25f;            // / sqrt(16)
    float mn = fmaxf(m, alpha);
    float sc = __expf(m - mn);          // m=-inf first iter -> 0
    float e  = __expf(alpha - mn);
    lsum = lsum*sc + e;
    a0   = a0*sc + e*vv.x;
    a1   = a1*sc + e*vv.y;
    m = mn;
  }
  float inv = (lsum > 0.f) ? 1.f/lsum : 0.f;
  float2 skip = *(const float2*)(h + n*HD + c0);
  float o0 = fmaxf(a0*inv + skip.x, 0.f);
  float o1 = fmaxf(a1*inv + skip.y, 0.f);
  *(float2*)(h + n*HD + c0) = make_float2(o0, o1);
}

// ---------------- BN stats: per-channel sum & sumsq ----------------
__global__ __launch_bounds__(256) void k_bnstats(const float* __restrict__ h, float* __restrict__ stats, int N){
  __shared__ float sm[512];
  int t = threadIdx.x;
  int c = t & 127, half = t >> 7;
  int r0 = blockIdx.x * 256;
  int rend = min(r0 + 256, N);
  float s = 0.f, sq = 0.f;
  for (int r = r0 + half; r < rend; r += 2){
    float val = h[r*HD + c];
    s += val; sq += val*val;
  }
  sm[t] = s; sm[256 + t] = sq;
  __syncthreads();
  if (t < 128){
    atomicAdd(&stats[c],       sm[t] + sm[t + 128]);
    atomicAdd(&stats[128 + c], sm[256 + t] + sm[256 + t + 128]);
  }
}

// ---------------- BN finalize (+ optional residual) ----------------
__global__ __launch_bounds__(256) void k_bnfin(
    const float* __restrict__ h, float* __restrict__ x, const float* __restrict__ stats,
    const float* __restrict__ gamma, const float* __restrict__ beta, int N, int resid, float invN){
  int idx = blockIdx.x*256 + threadIdx.x;
  if (idx >= N*HD) return;
  int c = idx & 127;
  float mu  = stats[c] * invN;
  float var = stats[128 + c] * invN - mu*mu;
  float scl = rsqrtf(var + 1e-5f) * gamma[c];
  float o = (h[idx] - mu) * scl + beta[c];
  x[idx] = resid ? (x[idx] + o) : o;
}

// ---------------- global mean pool + regression head ----------------
__global__ __launch_bounds__(256) void k_pool(
    const float* __restrict__ x, const int* __restrict__ gcnt,
    const float* __restrict__ Wr, const float* __restrict__ br,
    float* __restrict__ out, int N){
  __shared__ float sm[256];
  __shared__ float xmv[128];
  int g = blockIdx.x;
  int t = threadIdx.x;
  int start = 0;
  for (int i = 0; i < g; ++i) start += gcnt[i];
  int cnt = gcnt[g];
  int c = t & 127, half = t >> 7;
  float s = 0.f;
  for (int r = start + half; r < start + cnt; r += 2) s += x[r*HD + c];
  sm[t] = s;
  __syncthreads();
  if (t < 128){
    float xm = (sm[t] + sm[t + 128]) / fmaxf((float)cnt, 1.f);
    out[NGRAPH + g*HD + t] = xm;
    xmv[t] = xm;
  }
  __syncthreads();
  if (t < 64){
    float p = xmv[t]*Wr[t] + xmv[t + 64]*Wr[t + 64];
    p += __shfl_xor(p, 1);
    p += __shfl_xor(p, 2);
    p += __shfl_xor(p, 4);
    p += __shfl_xor(p, 8);
    p += __shfl_xor(p, 16);
    p += __shfl_xor(p, 32);
    if (t == 0) out[g] = p + br[0];
  }
}

extern "C" void kernel_launch(void* const* d_in, const int* in_sizes, int n_in,
                              void* d_out, int out_size, void* d_ws, size_t ws_size,
                              hipStream_t stream){
  const float* X     = (const float*)d_in[0];
  const int*   ei    = (const int*)  d_in[1];
  const int*   batch = (const int*)  d_in[2];
  const float* Wq1 = (const float*)d_in[3];  const float* bq1 = (const float*)d_in[4];
  const float* Wk1 = (const float*)d_in[5];  const float* bk1 = (const float*)d_in[6];
  const float* Wv1 = (const float*)d_in[7];  const float* bv1 = (const float*)d_in[8];
  const float* Ws1 = (const float*)d_in[9];  const float* bs1 = (const float*)d_in[10];
  const float* Wq  = (const float*)d_in[11]; const float* bq  = (const float*)d_in[12];
  const float* Wk  = (const float*)d_in[13]; const float* bk  = (const float*)d_in[14];
  const float* Wv  = (const float*)d_in[15]; const float* bv  = (const float*)d_in[16];
  const float* Ws  = (const float*)d_in[17]; const float* bs  = (const float*)d_in[18];
  const float* bn_g= (const float*)d_in[19]; const float* bn_b= (const float*)d_in[20];
  const float* Wr  = (const float*)d_in[21]; const float* br  = (const float*)d_in[22];

  const int N = in_sizes[0];        // X is (N,1)
  const int E = in_sizes[1] / 2;

  const int* src = ei;
  const int* dst = ei + E;

  // workspace carve (256B aligned)
  char* p = (char*)d_ws;
  auto alloc = [&](size_t bytes) -> void* {
    void* r = (void*)p;
    p += (bytes + 255) & ~(size_t)255;
    return r;
  };
  int* deg    = (int*)alloc((size_t)N * 4);
  int* cursor = (int*)alloc((size_t)N * 4);
  int* gcnt   = (int*)alloc(NGRAPH * 4);
  char* zero_end = p;
  int* rp     = (int*)alloc((size_t)(N + 1) * 4);
  int* bt     = (int*)alloc(256 * 4);
  int* bo     = (int*)alloc(256 * 4);
  int* srcs   = (int*)alloc((size_t)E * 4);
  float* stats= (float*)alloc(256 * 4);
  float* q    = (float*)alloc((size_t)N * HD * 4);
  float* k    = (float*)alloc((size_t)N * HD * 4);
  float* v    = (float*)alloc((size_t)N * HD * 4);
  float* h    = (float*)alloc((size_t)N * HD * 4);
  float* x    = (float*)alloc((size_t)N * HD * 4);

  // zero deg/cursor/gcnt in one shot
  hipMemsetAsync(deg, 0, (size_t)(zero_end - (char*)deg), stream);

  const int NB  = (N + 255) / 256;
  const int EB  = (E + 255) / 256;
  const int NCB = (N * HD + 255) / 256;
  const int ATB = (N * 64 + 255) / 256;
  const float invN = 1.f / (float)N;

  // CSR build
  k_count  <<<EB, 256, 0, stream>>>(dst, deg, E);
  k_scan1  <<<NB, 256, 0, stream>>>(deg, rp, bt, N);
  k_scan2  <<<1, 256, 0, stream>>>(bt, bo, NB);
  k_scan3  <<<NB, 256, 0, stream>>>(rp, bo, N);
  k_scatter<<<EB, 256, 0, stream>>>(src, dst, rp, cursor, srcs, E);
  k_gcount <<<NB, 256, 0, stream>>>(batch, gcnt, N);

  // layer 1
  k_layer1<<<NCB, 256, 0, stream>>>(X, Wq1,bq1, Wk1,bk1, Wv1,bv1, Ws1,bs1, q, k, v, h, N);
  k_attn  <<<ATB, 256, 0, stream>>>(q, k, v, h, rp, srcs, N);
  hipMemsetAsync(stats, 0, 256 * 4, stream);
  k_bnstats<<<NB, 256, 0, stream>>>(h, stats, N);
  k_bnfin <<<NCB, 256, 0, stream>>>(h, x, stats, bn_g, bn_b, N, 0, invN);

  // layers 2..5
  for (int l = 0; l < 4; ++l){
    const float* Wql = Wq + (size_t)l*HD*HD;  const float* bql = bq + (size_t)l*HD;
    const float* Wkl = Wk + (size_t)l*HD*HD;  const float* bkl = bk + (size_t)l*HD;
    const float* Wvl = Wv + (size_t)l*HD*HD;  const float* bvl = bv + (size_t)l*HD;
    const float* Wsl = Ws + (size_t)l*HD*HD;  const float* bsl = bs + (size_t)l*HD;
    k_gemm<<<dim3((N + 63) / 64, 8), 256, 0, stream>>>(
        x, Wql, Wkl, Wvl, Wsl, bql, bkl, bvl, bsl, q, k, v, h, N);
    k_attn<<<ATB, 256, 0, stream>>>(q, k, v, h, rp, srcs, N);
    hipMemsetAsync(stats, 0, 256 * 4, stream);
    k_bnstats<<<NB, 256, 0, stream>>>(h, stats, N);
    k_bnfin<<<NCB, 256, 0, stream>>>(h, x, stats, bn_g + (size_t)(l+1)*HD, bn_b + (size_t)(l+1)*HD, N, 1, invN);
  }

  // pool + head
  k_pool<<<NGRAPH, 256, 0, stream>>>(x, gcnt, Wr, br, (float*)d_out, N);
}

// Round 2
// 1827.860 us; speedup vs baseline: 1.0135x; 1.0135x over previous
//
#include <hip/hip_runtime.h>
#include <math.h>

#define HD 128
#define NGRAPH 64

__device__ __forceinline__ float4 ld4(const float* p){ return *(const float4*)p; }

// ---------------- CSR build ----------------
__global__ __launch_bounds__(256) void k_count(const int* __restrict__ dst, int* __restrict__ deg, int E){
  int e = blockIdx.x*256 + threadIdx.x;
  if (e < E) atomicAdd(&deg[dst[e]], 1);
}

__global__ __launch_bounds__(256) void k_scan1(const int* __restrict__ deg, int* __restrict__ rp,
                                               int* __restrict__ bt, int N){
  __shared__ int sm[256];
  int i = blockIdx.x*256 + threadIdx.x;
  int v = (i < N) ? deg[i] : 0;
  sm[threadIdx.x] = v;
  __syncthreads();
  for (int off = 1; off < 256; off <<= 1){
    int t = (threadIdx.x >= (unsigned)off) ? sm[threadIdx.x - off] : 0;
    __syncthreads();
    sm[threadIdx.x] += t;
    __syncthreads();
  }
  if (i < N) rp[i+1] = sm[threadIdx.x];
  if (threadIdx.x == 255) bt[blockIdx.x] = sm[255];
  if (blockIdx.x == 0 && threadIdx.x == 0) rp[0] = 0;
}

__global__ __launch_bounds__(256) void k_scan2(const int* __restrict__ bt, int* __restrict__ bo, int NB){
  __shared__ int sm[256];
  int t = threadIdx.x;
  int v = (t < NB) ? bt[t] : 0;
  sm[t] = v;
  __syncthreads();
  for (int off = 1; off < 256; off <<= 1){
    int u = (t >= (unsigned)off) ? sm[t - off] : 0;
    __syncthreads();
    sm[t] += u;
    __syncthreads();
  }
  if (t < NB) bo[t] = sm[t] - v;   // exclusive offset per block
}

__global__ __launch_bounds__(256) void k_scan3(int* __restrict__ rp, const int* __restrict__ bo, int N){
  int i = blockIdx.x*256 + threadIdx.x;
  if (i < N) rp[i+1] += bo[i >> 8];
}

__global__ __launch_bounds__(256) void k_scatter(const int* __restrict__ src, const int* __restrict__ dst,
                                                 const int* __restrict__ rp, int* __restrict__ cursor,
                                                 int* __restrict__ srcs, int E){
  int e = blockIdx.x*256 + threadIdx.x;
  if (e < E){
    int d = dst[e];
    int pos = atomicAdd(&cursor[d], 1);
    srcs[rp[d] + pos] = src[e];
  }
}

// graph boundaries via binary search over the SORTED batch array — no atomics
__global__ __launch_bounds__(128) void k_gbounds(const int* __restrict__ batch, int* __restrict__ gstart, int N){
  int g = threadIdx.x;
  if (g > NGRAPH) return;
  int lo = 0, hi = N;
  while (lo < hi){
    int mid = (lo + hi) >> 1;
    if (batch[mid] < g) lo = mid + 1; else hi = mid;
  }
  gstart[g] = lo;   // first index with batch[i] >= g
}

// ---------------- layer 1 projection (in_dim = 1) ----------------
__global__ __launch_bounds__(256) void k_layer1(
    const float* __restrict__ X,
    const float* __restrict__ Wq1, const float* __restrict__ bq1,
    const float* __restrict__ Wk1, const float* __restrict__ bk1,
    const float* __restrict__ Wv1, const float* __restrict__ bv1,
    const float* __restrict__ Ws1, const float* __restrict__ bs1,
    float* __restrict__ q, float* __restrict__ k, float* __restrict__ v, float* __restrict__ h, int N){
  int idx = blockIdx.x*256 + threadIdx.x;
  if (idx >= N*HD) return;
  int n = idx >> 7, c = idx & 127;
  float xv = X[n];
  q[idx] = xv*Wq1[c] + bq1[c];
  k[idx] = xv*Wk1[c] + bk1[c];
  v[idx] = xv*Wv1[c] + bv1[c];
  h[idx] = xv*Ws1[c] + bs1[c];
}

// ---------------- fused QKVS GEMM: out[colgrp] = x @ W + b ----------------
// grid = (ceil(N/64), 8): blockIdx.y selects {q,k,v,h} x {cols 0-63, 64-127}
__global__ __launch_bounds__(256) void k_gemm(
    const float* __restrict__ x,
    const float* __restrict__ Wq, const float* __restrict__ Wk,
    const float* __restrict__ Wv, const float* __restrict__ Ws,
    const float* __restrict__ bq, const float* __restrict__ bk,
    const float* __restrict__ bv, const float* __restrict__ bs,
    float* __restrict__ q, float* __restrict__ k, float* __restrict__ v, float* __restrict__ h,
    int nrows){
  __shared__ float As[64*36];   // x tile [64 rows][32 k], stride 36
  __shared__ float Bs[32*64];   // W tile [32 k][64 cols]

  int wsel = blockIdx.y >> 1;
  int c0   = (blockIdx.y & 1) * 64;
  const float* W    = (wsel==0)?Wq:(wsel==1)?Wk:(wsel==2)?Wv:Ws;
  const float* bias = (wsel==0)?bq:(wsel==1)?bk:(wsel==2)?bv:bs;
  float* out        = (wsel==0)?q :(wsel==1)?k :(wsel==2)?v :h;

  int row0 = blockIdx.x * 64;
  int tid  = threadIdx.x;
  int tx = tid & 15, ty = tid >> 4;
  int r0 = ty*4, cc = tx*4;

  float acc[4][4] = {{0.f,0.f,0.f,0.f},{0.f,0.f,0.f,0.f},{0.f,0.f,0.f,0.f},{0.f,0.f,0.f,0.f}};

  for (int kc = 0; kc < 128; kc += 32){
    for (int i = tid; i < 512; i += 256){
      int r = i >> 3;
      int kk4 = (i & 7) << 2;
      int gr = row0 + r;
      float4 val = (gr < nrows) ? ld4(x + gr*HD + kc + kk4) : make_float4(0.f,0.f,0.f,0.f);
      *(float4*)&As[r*36 + kk4] = val;
    }
    for (int i = tid; i < 512; i += 256){
      int kk = i >> 4;
      int cc4 = (i & 15) << 2;
      *(float4*)&Bs[kk*64 + cc4] = ld4(W + (kc+kk)*HD + c0 + cc4);
    }
    __syncthreads();

    #pragma unroll
    for (int kk = 0; kk < 32; kk += 4){
      float a[4][4], b[4][4];
      #pragma unroll
      for (int i = 0; i < 4; ++i) *(float4*)a[i] = *(const float4*)&As[(r0+i)*36 + kk];
      #pragma unroll
      for (int j = 0; j < 4; ++j) *(float4*)b[j] = *(const float4*)&Bs[(kk+j)*64 + cc];
      #pragma unroll
      for (int i = 0; i < 4; ++i)
        #pragma unroll
        for (int p = 0; p < 4; ++p)
          #pragma unroll
          for (int j = 0; j < 4; ++j)
            acc[i][j] = fmaf(a[i][p], b[p][j], acc[i][j]);
    }
    __syncthreads();
  }

  #pragma unroll
  for (int i = 0; i < 4; ++i){
    int gr = row0 + r0 + i;
    if (gr < nrows){
      float4 ob;
      ob.x = acc[i][0] + bias[c0+cc+0];
      ob.y = acc[i][1] + bias[c0+cc+1];
      ob.z = acc[i][2] + bias[c0+cc+2];
      ob.w = acc[i][3] + bias[c0+cc+3];
      *(float4*)(out + gr*HD + c0 + cc) = ob;
    }
  }
}

// ---------------- attention: one wave per dst node, online softmax ----------------
__global__ __launch_bounds__(256) void k_attn(
    const float* __restrict__ q, const float* __restrict__ k, const float* __restrict__ v,
    float* __restrict__ h, const int* __restrict__ rp, const int* __restrict__ srcs, int N){
  int wave = (blockIdx.x*256 + threadIdx.x) >> 6;
  int lane = threadIdx.x & 63;
  if (wave >= N) return;
  int n = wave;
  int c0 = lane * 2;
  float2 qv = *(const float2*)(q + n*HD + c0);
  int beg = rp[n], end = rp[n+1];
  float m = -INFINITY, lsum = 0.f, a0 = 0.f, a1 = 0.f;
  for (int t = beg; t < end; ++t){
    int s = srcs[t];
    float2 kv = *(const float2*)(k + s*HD + c0);
    float2 vv = *(const float2*)(v + s*HD + c0);
    float p = qv.x*kv.x + qv.y*kv.y;
    p += __shfl_xor(p, 1);
    p += __shfl_xor(p, 2);
    p += __shfl_xor(p, 4);
    float alpha = p * 0.25f;            // / sqrt(16)
    float mn = fmaxf(m, alpha);
    float sc = __expf(m - mn);          // m=-inf first iter -> 0
    float e  = __expf(alpha - mn);
    lsum = lsum*sc + e;
    a0   = a0*sc + e*vv.x;
    a1   = a1*sc + e*vv.y;
    m = mn;
  }
  float inv = (lsum > 0.f) ? 1.f/lsum : 0.f;
  float2 skip = *(const float2*)(h + n*HD + c0);
  float o0 = fmaxf(a0*inv + skip.x, 0.f);
  float o1 = fmaxf(a1*inv + skip.y, 0.f);
  *(float2*)(h + n*HD + c0) = make_float2(o0, o1);
}

// ---------------- BN stats: per-block partials, no atomics ----------------
__global__ __launch_bounds__(256) void k_bnstats(const float* __restrict__ h, float* __restrict__ partials, int N){
  __shared__ float sm[512];
  int t = threadIdx.x;
  int c = t & 127, half = t >> 7;
  int r0 = blockIdx.x * 256;
  int rend = min(r0 + 256, N);
  float s = 0.f, sq = 0.f;
  for (int r = r0 + half; r < rend; r += 2){
    float val = h[r*HD + c];
    s += val; sq += val*val;
  }
  sm[t] = s; sm[256 + t] = sq;
  __syncthreads();
  if (t < 128){
    partials[(size_t)blockIdx.x*256 + t]       = sm[t] + sm[t + 128];
    partials[(size_t)blockIdx.x*256 + 128 + t] = sm[256 + t] + sm[256 + t + 128];
  }
}

__global__ __launch_bounds__(256) void k_bnreduce(const float* __restrict__ partials,
                                                  float* __restrict__ stats, int NB){
  int t = threadIdx.x;   // 0..255 -> stat entry
  float s = 0.f;
  for (int b = 0; b < NB; ++b) s += partials[(size_t)b*256 + t];
  stats[t] = s;
}

// ---------------- BN finalize (+ optional residual) ----------------
__global__ __launch_bounds__(256) void k_bnfin(
    const float* __restrict__ h, float* __restrict__ x, const float* __restrict__ stats,
    const float* __restrict__ gamma, const float* __restrict__ beta, int N, int resid, float invN){
  int idx = blockIdx.x*256 + threadIdx.x;
  if (idx >= N*HD) return;
  int c = idx & 127;
  float mu  = stats[c] * invN;
  float var = stats[128 + c] * invN - mu*mu;
  float scl = rsqrtf(var + 1e-5f) * gamma[c];
  float o = (h[idx] - mu) * scl + beta[c];
  x[idx] = resid ? (x[idx] + o) : o;
}

// ---------------- global mean pool + regression head ----------------
__global__ __launch_bounds__(256) void k_pool(
    const float* __restrict__ x, const int* __restrict__ gstart,
    const float* __restrict__ Wr, const float* __restrict__ br,
    float* __restrict__ out, int N){
  __shared__ float sm[256];
  __shared__ float xmv[128];
  int g = blockIdx.x;
  int t = threadIdx.x;
  int start = gstart[g];
  int cnt   = gstart[g+1] - start;
  int c = t & 127, half = t >> 7;
  float s = 0.f;
  for (int r = start + half; r < start + cnt; r += 2) s += x[r*HD + c];
  sm[t] = s;
  __syncthreads();
  if (t < 128){
    float xm = (sm[t] + sm[t + 128]) / fmaxf((float)cnt, 1.f);
    out[NGRAPH + g*HD + t] = xm;
    xmv[t] = xm;
  }
  __syncthreads();
  if (t < 64){
    float p = xmv[t]*Wr[t] + xmv[t + 64]*Wr[t + 64];
    p += __shfl_xor(p, 1);
    p += __shfl_xor(p, 2);
    p += __shfl_xor(p, 4);
    p += __shfl_xor(p, 8);
    p += __shfl_xor(p, 16);
    p += __shfl_xor(p, 32);
    if (t == 0) out[g] = p + br[0];
  }
}

extern "C" void kernel_launch(void* const* d_in, const int* in_sizes, int n_in,
                              void* d_out, int out_size, void* d_ws, size_t ws_size,
                              hipStream_t stream){
  const float* X     = (const float*)d_in[0];
  const int*   ei    = (const int*)  d_in[1];
  const int*   batch = (const int*)  d_in[2];
  const float* Wq1 = (const float*)d_in[3];  const float* bq1 = (const float*)d_in[4];
  const float* Wk1 = (const float*)d_in[5];  const float* bk1 = (const float*)d_in[6];
  const float* Wv1 = (const float*)d_in[7];  const float* bv1 = (const float*)d_in[8];
  const float* Ws1 = (const float*)d_in[9];  const float* bs1 = (const float*)d_in[10];
  const float* Wq  = (const float*)d_in[11]; const float* bq  = (const float*)d_in[12];
  const float* Wk  = (const float*)d_in[13]; const float* bk  = (const float*)d_in[14];
  const float* Wv  = (const float*)d_in[15]; const float* bv  = (const float*)d_in[16];
  const float* Ws  = (const float*)d_in[17]; const float* bs  = (const float*)d_in[18];
  const float* bn_g= (const float*)d_in[19]; const float* bn_b= (const float*)d_in[20];
  const float* Wr  = (const float*)d_in[21]; const float* br  = (const float*)d_in[22];

  const int N = in_sizes[0];
  const int E = in_sizes[1] / 2;

  const int* src = ei;
  const int* dst = ei + E;

  char* p = (char*)d_ws;
  auto alloc = [&](size_t bytes) -> void* {
    void* r = (void*)p;
    p += (bytes + 255) & ~(size_t)255;
    return r;
  };
  int* deg    = (int*)alloc((size_t)N * 4);
  int* cursor = (int*)alloc((size_t)N * 4);
  char* zero_end = p;
  int* rp     = (int*)alloc((size_t)(N + 1) * 4);
  int* bt     = (int*)alloc(256 * 4);
  int* bo     = (int*)alloc(256 * 4);
  int* gstart = (int*)alloc((NGRAPH + 1) * 4);
  int* srcs   = (int*)alloc((size_t)E * 4);
  float* stats= (float*)alloc(256 * 4);
  float* partials = (float*)alloc((size_t)256 * 256 * 4);
  float* q    = (float*)alloc((size_t)N * HD * 4);
  float* k    = (float*)alloc((size_t)N * HD * 4);
  float* v    = (float*)alloc((size_t)N * HD * 4);
  float* h    = (float*)alloc((size_t)N * HD * 4);
  float* x    = (float*)alloc((size_t)N * HD * 4);

  hipMemsetAsync(deg, 0, (size_t)(zero_end - (char*)deg), stream);

  const int NB  = (N + 255) / 256;
  const int EB  = (E + 255) / 256;
  const int NCB = (N * HD + 255) / 256;
  const int ATB = (N * 64 + 255) / 256;
  const float invN = 1.f / (float)N;

  // CSR build + graph bounds
  k_count  <<<EB, 256, 0, stream>>>(dst, deg, E);
  k_scan1  <<<NB, 256, 0, stream>>>(deg, rp, bt, N);
  k_scan2  <<<1, 256, 0, stream>>>(bt, bo, NB);
  k_scan3  <<<NB, 256, 0, stream>>>(rp, bo, N);
  k_scatter<<<EB, 256, 0, stream>>>(src, dst, rp, cursor, srcs, E);
  k_gbounds<<<1, 128, 0, stream>>>(batch, gstart, N);

  // layer 1
  k_layer1<<<NCB, 256, 0, stream>>>(X, Wq1,bq1, Wk1,bk1, Wv1,bv1, Ws1,bs1, q, k, v, h, N);
  k_attn  <<<ATB, 256, 0, stream>>>(q, k, v, h, rp, srcs, N);
  k_bnstats<<<NB, 256, 0, stream>>>(h, partials, N);
  k_bnreduce<<<1, 256, 0, stream>>>(partials, stats, NB);
  k_bnfin <<<NCB, 256, 0, stream>>>(h, x, stats, bn_g, bn_b, N, 0, invN);

  // layers 2..5
  for (int l = 0; l < 4; ++l){
    const float* Wql = Wq + (size_t)l*HD*HD;  const float* bql = bq + (size_t)l*HD;
    const float* Wkl = Wk + (size_t)l*HD*HD;  const float* bkl = bk + (size_t)l*HD;
    const float* Wvl = Wv + (size_t)l*HD*HD;  const float* bvl = bv + (size_t)l*HD;
    const float* Wsl = Ws + (size_t)l*HD*HD;  const float* bsl = bs + (size_t)l*HD;
    k_gemm<<<dim3((N + 63) / 64, 8), 256, 0, stream>>>(
        x, Wql, Wkl, Wvl, Wsl, bql, bkl, bvl, bsl, q, k, v, h, N);
    k_attn<<<ATB, 256, 0, stream>>>(q, k, v, h, rp, srcs, N);
    k_bnstats<<<NB, 256, 0, stream>>>(h, partials, N);
    k_bnreduce<<<1, 256, 0, stream>>>(partials, stats, NB);
    k_bnfin<<<NCB, 256, 0, stream>>>(h, x, stats, bn_g + (size_t)(l+1)*HD, bn_b + (size_t)(l+1)*HD, N, 1, invN);
  }

  // pool + head
  k_pool<<<NGRAPH, 256, 0, stream>>>(x, gstart, Wr, br, (float*)d_out, N);
}

// Round 3
// 1463.254 us; speedup vs baseline: 1.2660x; 1.2492x over previous
//
#include <hip/hip_runtime.h>
#include <hip/hip_fp16.h>
#include <math.h>

#define HD 128
#define NGRAPH 64

__device__ __forceinline__ float4 ld4(const float* p){ return *(const float4*)p; }
__device__ __forceinline__ unsigned h2bits(__half2 h){ return *(unsigned*)&h; }

// ---------------- CSR build ----------------
__global__ __launch_bounds__(256) void k_count(const int* __restrict__ dst, int* __restrict__ deg, int E){
  int e = blockIdx.x*256 + threadIdx.x;
  if (e < E) atomicAdd(&deg[dst[e]], 1);
}

__global__ __launch_bounds__(256) void k_scan1(const int* __restrict__ deg, int* __restrict__ rp,
                                               int* __restrict__ bt, int N){
  __shared__ int sm[256];
  int i = blockIdx.x*256 + threadIdx.x;
  int v = (i < N) ? deg[i] : 0;
  sm[threadIdx.x] = v;
  __syncthreads();
  for (int off = 1; off < 256; off <<= 1){
    int t = (threadIdx.x >= (unsigned)off) ? sm[threadIdx.x - off] : 0;
    __syncthreads();
    sm[threadIdx.x] += t;
    __syncthreads();
  }
  if (i < N) rp[i+1] = sm[threadIdx.x];
  if (threadIdx.x == 255) bt[blockIdx.x] = sm[255];
  if (blockIdx.x == 0 && threadIdx.x == 0) rp[0] = 0;
}

__global__ __launch_bounds__(256) void k_scan2(const int* __restrict__ bt, int* __restrict__ bo, int NB){
  __shared__ int sm[256];
  int t = threadIdx.x;
  int v = (t < NB) ? bt[t] : 0;
  sm[t] = v;
  __syncthreads();
  for (int off = 1; off < 256; off <<= 1){
    int u = (t >= (unsigned)off) ? sm[t - off] : 0;
    __syncthreads();
    sm[t] += u;
    __syncthreads();
  }
  if (t < NB) bo[t] = sm[t] - v;
}

__global__ __launch_bounds__(256) void k_scan3(int* __restrict__ rp, const int* __restrict__ bo, int N){
  int i = blockIdx.x*256 + threadIdx.x;
  if (i < N) rp[i+1] += bo[i >> 8];
}

__global__ __launch_bounds__(256) void k_scatter(const int* __restrict__ src, const int* __restrict__ dst,
                                                 const int* __restrict__ rp, int* __restrict__ cursor,
                                                 int* __restrict__ srcs, int E){
  int e = blockIdx.x*256 + threadIdx.x;
  if (e < E){
    int d = dst[e];
    int pos = atomicAdd(&cursor[d], 1);
    srcs[rp[d] + pos] = src[e];
  }
}

// graph boundaries via binary search over SORTED batch — no atomics
__global__ __launch_bounds__(128) void k_gbounds(const int* __restrict__ batch, int* __restrict__ gstart, int N){
  int g = threadIdx.x;
  if (g > NGRAPH) return;
  int lo = 0, hi = N;
  while (lo < hi){
    int mid = (lo + hi) >> 1;
    if (batch[mid] < g) lo = mid + 1; else hi = mid;
  }
  gstart[g] = lo;
}

// ---------------- layer 1 projection (in_dim = 1) ----------------
// q,h f32; k,v packed fp16 into kv slots: per node 32 x uint4 {k01,k23,v01,v23}
__global__ __launch_bounds__(256) void k_layer1(
    const float* __restrict__ X,
    const float* __restrict__ Wq1, const float* __restrict__ bq1,
    const float* __restrict__ Wk1, const float* __restrict__ bk1,
    const float* __restrict__ Wv1, const float* __restrict__ bv1,
    const float* __restrict__ Ws1, const float* __restrict__ bs1,
    float* __restrict__ q, uint4* __restrict__ kv, float* __restrict__ h, int N){
  int idx = blockIdx.x*256 + threadIdx.x;
  if (idx >= N*32) return;
  int n = idx >> 5, s4 = idx & 31, c = s4 << 2;
  float xv = X[n];
  float qv[4], kk[4], vv[4], hv[4];
  #pragma unroll
  for (int i = 0; i < 4; ++i){
    qv[i] = xv*Wq1[c+i] + bq1[c+i];
    kk[i] = xv*Wk1[c+i] + bk1[c+i];
    vv[i] = xv*Wv1[c+i] + bv1[c+i];
    hv[i] = xv*Ws1[c+i] + bs1[c+i];
  }
  *(float4*)(q + (size_t)n*HD + c) = make_float4(qv[0],qv[1],qv[2],qv[3]);
  *(float4*)(h + (size_t)n*HD + c) = make_float4(hv[0],hv[1],hv[2],hv[3]);
  uint4 g;
  g.x = h2bits(__floats2half2_rn(kk[0], kk[1]));
  g.y = h2bits(__floats2half2_rn(kk[2], kk[3]));
  g.z = h2bits(__floats2half2_rn(vv[0], vv[1]));
  g.w = h2bits(__floats2half2_rn(vv[2], vv[3]));
  kv[(size_t)n*32 + s4] = g;
}

// ---------------- fused QKVS GEMM ----------------
// grid = (ceil(N/64), 8): blockIdx.y = {q,k,v,h} x {cols 0-63, 64-127}
// q,h -> f32 arrays; k,v -> packed fp16 kv slots
__global__ __launch_bounds__(256) void k_gemm(
    const float* __restrict__ x,
    const float* __restrict__ Wq, const float* __restrict__ Wk,
    const float* __restrict__ Wv, const float* __restrict__ Ws,
    const float* __restrict__ bq, const float* __restrict__ bk,
    const float* __restrict__ bv, const float* __restrict__ bs,
    float* __restrict__ q, unsigned* __restrict__ kvbuf, float* __restrict__ h,
    int nrows){
  __shared__ float As[64*36];
  __shared__ float Bs[32*64];

  int wsel = blockIdx.y >> 1;
  int c0   = (blockIdx.y & 1) * 64;
  const float* W    = (wsel==0)?Wq:(wsel==1)?Wk:(wsel==2)?Wv:Ws;
  const float* bias = (wsel==0)?bq:(wsel==1)?bk:(wsel==2)?bv:bs;

  int row0 = blockIdx.x * 64;
  int tid  = threadIdx.x;
  int tx = tid & 15, ty = tid >> 4;
  int r0 = ty*4, cc = tx*4;

  float acc[4][4] = {{0.f,0.f,0.f,0.f},{0.f,0.f,0.f,0.f},{0.f,0.f,0.f,0.f},{0.f,0.f,0.f,0.f}};

  for (int kc = 0; kc < 128; kc += 32){
    for (int i = tid; i < 512; i += 256){
      int r = i >> 3;
      int kk4 = (i & 7) << 2;
      int gr = row0 + r;
      float4 val = (gr < nrows) ? ld4(x + (size_t)gr*HD + kc + kk4) : make_float4(0.f,0.f,0.f,0.f);
      *(float4*)&As[r*36 + kk4] = val;
    }
    for (int i = tid; i < 512; i += 256){
      int kk = i >> 4;
      int cc4 = (i & 15) << 2;
      *(float4*)&Bs[kk*64 + cc4] = ld4(W + (size_t)(kc+kk)*HD + c0 + cc4);
    }
    __syncthreads();

    #pragma unroll
    for (int kk = 0; kk < 32; kk += 4){
      float a[4][4], b[4][4];
      #pragma unroll
      for (int i = 0; i < 4; ++i) *(float4*)a[i] = *(const float4*)&As[(r0+i)*36 + kk];
      #pragma unroll
      for (int j = 0; j < 4; ++j) *(float4*)b[j] = *(const float4*)&Bs[(kk+j)*64 + cc];
      #pragma unroll
      for (int i = 0; i < 4; ++i)
        #pragma unroll
        for (int p = 0; p < 4; ++p)
          #pragma unroll
          for (int j = 0; j < 4; ++j)
            acc[i][j] = fmaf(a[i][p], b[p][j], acc[i][j]);
    }
    __syncthreads();
  }

  int cG = c0 + cc;
  float b0 = bias[cG+0], b1 = bias[cG+1], b2 = bias[cG+2], b3 = bias[cG+3];
  if (wsel == 0 || wsel == 3){
    float* out = (wsel == 0) ? q : h;
    #pragma unroll
    for (int i = 0; i < 4; ++i){
      int gr = row0 + r0 + i;
      if (gr < nrows){
        *(float4*)(out + (size_t)gr*HD + cG) =
          make_float4(acc[i][0]+b0, acc[i][1]+b1, acc[i][2]+b2, acc[i][3]+b3);
      }
    }
  } else {
    int off = (wsel == 2) ? 2 : 0;   // k -> .xy, v -> .zw of the uint4 slot
    #pragma unroll
    for (int i = 0; i < 4; ++i){
      int gr = row0 + r0 + i;
      if (gr < nrows){
        uint2 w;
        w.x = h2bits(__floats2half2_rn(acc[i][0]+b0, acc[i][1]+b1));
        w.y = h2bits(__floats2half2_rn(acc[i][2]+b2, acc[i][3]+b3));
        *(uint2*)&kvbuf[(size_t)gr*HD + cG + off] = w;
      }
    }
  }
}

// ---------------- attention: one wave per dst node, 2 edges per iteration ----------------
__global__ __launch_bounds__(256) void k_attn(
    const float* __restrict__ q, const uint4* __restrict__ kv,
    float* __restrict__ h, const int* __restrict__ rp, const int* __restrict__ srcs, int N){
  int wid = (blockIdx.x*256 + threadIdx.x) >> 6;
  if (wid >= N) return;
  int lane = threadIdx.x & 63;
  int half = lane >> 5, l5 = lane & 31;
  int n = wid;
  float4 qv = *(const float4*)(q + (size_t)n*HD + (l5 << 2));
  int beg = rp[n], end = rp[n+1];

  float m = -INFINITY, lsum = 0.f;
  float a0 = 0.f, a1 = 0.f, a2 = 0.f, a3 = 0.f;

  auto upd = [&](uint4 g, bool valid){
    float2 k01 = __half22float2(*(const __half2*)&g.x);
    float2 k23 = __half22float2(*(const __half2*)&g.y);
    float2 v01 = __half22float2(*(const __half2*)&g.z);
    float2 v23 = __half22float2(*(const __half2*)&g.w);
    float pd = qv.x*k01.x + qv.y*k01.y + qv.z*k23.x + qv.w*k23.y;
    pd += __shfl_xor(pd, 1);
    pd += __shfl_xor(pd, 2);      // sum over 4 lanes = 16 channels = one head
    if (valid){
      float alpha = pd * 0.25f;   // / sqrt(16)
      float mn = fmaxf(m, alpha);
      float sc = __expf(m - mn);  // first valid edge: exp(-inf)=0
      float e  = __expf(alpha - mn);
      lsum = lsum*sc + e;
      a0 = a0*sc + e*v01.x;
      a1 = a1*sc + e*v01.y;
      a2 = a2*sc + e*v23.x;
      a3 = a3*sc + e*v23.y;
      m = mn;
    }
  };

  for (int cb = beg; cb < end; cb += 64){
    int cnt = min(64, end - cb);
    int s_pre = (cb + lane < end) ? srcs[cb + lane] : 0;
    int npair = (cnt + 1) >> 1;
    int t = 0;
    for (; t + 2 <= npair; t += 2){
      int e0 = 2*t + half, e1 = e0 + 2;
      int s0 = __shfl(s_pre, e0);
      int s1 = __shfl(s_pre, e1);
      uint4 g0 = kv[(size_t)s0*32 + l5];
      uint4 g1 = kv[(size_t)s1*32 + l5];
      upd(g0, e0 < cnt);
      upd(g1, e1 < cnt);
    }
    for (; t < npair; ++t){
      int e0 = 2*t + half;
      int s0 = __shfl(s_pre, e0);
      uint4 g0 = kv[(size_t)s0*32 + l5];
      upd(g0, e0 < cnt);
    }
  }

  // merge the two half-wave online-softmax streams
  float m_o  = __shfl_xor(m, 32);
  float l_o  = __shfl_xor(lsum, 32);
  float x0 = __shfl_xor(a0, 32);
  float x1 = __shfl_xor(a1, 32);
  float x2 = __shfl_xor(a2, 32);
  float x3 = __shfl_xor(a3, 32);
  float mn = fmaxf(m, m_o);
  float sc_s = (m   > -INFINITY) ? __expf(m   - mn) : 0.f;
  float sc_o = (m_o > -INFINITY) ? __expf(m_o - mn) : 0.f;
  lsum = lsum*sc_s + l_o*sc_o;
  a0 = a0*sc_s + x0*sc_o;
  a1 = a1*sc_s + x1*sc_o;
  a2 = a2*sc_s + x2*sc_o;
  a3 = a3*sc_s + x3*sc_o;
  float inv = (lsum > 0.f) ? 1.f/lsum : 0.f;

  if (half == 0){
    float4 skip = *(const float4*)(h + (size_t)n*HD + (l5 << 2));
    float4 o;
    o.x = fmaxf(a0*inv + skip.x, 0.f);
    o.y = fmaxf(a1*inv + skip.y, 0.f);
    o.z = fmaxf(a2*inv + skip.z, 0.f);
    o.w = fmaxf(a3*inv + skip.w, 0.f);
    *(float4*)(h + (size_t)n*HD + (l5 << 2)) = o;
  }
}

// ---------------- BN stats: per-block partials, no atomics ----------------
__global__ __launch_bounds__(256) void k_bnstats(const float* __restrict__ h, float* __restrict__ partials, int N){
  __shared__ float sm[512];
  int t = threadIdx.x;
  int c = t & 127, half = t >> 7;
  int r0 = blockIdx.x * 256;
  int rend = min(r0 + 256, N);
  float s = 0.f, sq = 0.f;
  for (int r = r0 + half; r < rend; r += 2){
    float val = h[(size_t)r*HD + c];
    s += val; sq += val*val;
  }
  sm[t] = s; sm[256 + t] = sq;
  __syncthreads();
  if (t < 128){
    partials[(size_t)blockIdx.x*256 + t]       = sm[t] + sm[t + 128];
    partials[(size_t)blockIdx.x*256 + 128 + t] = sm[256 + t] + sm[256 + t + 128];
  }
}

__global__ __launch_bounds__(256) void k_bnreduce(const float* __restrict__ partials,
                                                  float* __restrict__ stats, int NB){
  int t = threadIdx.x;
  float s = 0.f;
  for (int b = 0; b < NB; ++b) s += partials[(size_t)b*256 + t];
  stats[t] = s;
}

// ---------------- BN finalize (+ optional residual) ----------------
__global__ __launch_bounds__(256) void k_bnfin(
    const float* __restrict__ h, float* __restrict__ x, const float* __restrict__ stats,
    const float* __restrict__ gamma, const float* __restrict__ beta, int N, int resid, float invN){
  int idx = blockIdx.x*256 + threadIdx.x;
  if (idx >= N*HD) return;
  int c = idx & 127;
  float mu  = stats[c] * invN;
  float var = stats[128 + c] * invN - mu*mu;
  float scl = rsqrtf(var + 1e-5f) * gamma[c];
  float o = (h[idx] - mu) * scl + beta[c];
  x[idx] = resid ? (x[idx] + o) : o;
}

// ---------------- global mean pool + regression head ----------------
__global__ __launch_bounds__(256) void k_pool(
    const float* __restrict__ x, const int* __restrict__ gstart,
    const float* __restrict__ Wr, const float* __restrict__ br,
    float* __restrict__ out, int N){
  __shared__ float sm[256];
  __shared__ float xmv[128];
  int g = blockIdx.x;
  int t = threadIdx.x;
  int start = gstart[g];
  int cnt   = gstart[g+1] - start;
  int c = t & 127, half = t >> 7;
  float s = 0.f;
  for (int r = start + half; r < start + cnt; r += 2) s += x[(size_t)r*HD + c];
  sm[t] = s;
  __syncthreads();
  if (t < 128){
    float xm = (sm[t] + sm[t + 128]) / fmaxf((float)cnt, 1.f);
    out[NGRAPH + g*HD + t] = xm;
    xmv[t] = xm;
  }
  __syncthreads();
  if (t < 64){
    float p = xmv[t]*Wr[t] + xmv[t + 64]*Wr[t + 64];
    p += __shfl_xor(p, 1);
    p += __shfl_xor(p, 2);
    p += __shfl_xor(p, 4);
    p += __shfl_xor(p, 8);
    p += __shfl_xor(p, 16);
    p += __shfl_xor(p, 32);
    if (t == 0) out[g] = p + br[0];
  }
}

extern "C" void kernel_launch(void* const* d_in, const int* in_sizes, int n_in,
                              void* d_out, int out_size, void* d_ws, size_t ws_size,
                              hipStream_t stream){
  const float* X     = (const float*)d_in[0];
  const int*   ei    = (const int*)  d_in[1];
  const int*   batch = (const int*)  d_in[2];
  const float* Wq1 = (const float*)d_in[3];  const float* bq1 = (const float*)d_in[4];
  const float* Wk1 = (const float*)d_in[5];  const float* bk1 = (const float*)d_in[6];
  const float* Wv1 = (const float*)d_in[7];  const float* bv1 = (const float*)d_in[8];
  const float* Ws1 = (const float*)d_in[9];  const float* bs1 = (const float*)d_in[10];
  const float* Wq  = (const float*)d_in[11]; const float* bq  = (const float*)d_in[12];
  const float* Wk  = (const float*)d_in[13]; const float* bk  = (const float*)d_in[14];
  const float* Wv  = (const float*)d_in[15]; const float* bv  = (const float*)d_in[16];
  const float* Ws  = (const float*)d_in[17]; const float* bs  = (const float*)d_in[18];
  const float* bn_g= (const float*)d_in[19]; const float* bn_b= (const float*)d_in[20];
  const float* Wr  = (const float*)d_in[21]; const float* br  = (const float*)d_in[22];

  const int N = in_sizes[0];
  const int E = in_sizes[1] / 2;

  const int* src = ei;
  const int* dst = ei + E;

  char* p = (char*)d_ws;
  auto alloc = [&](size_t bytes) -> void* {
    void* r = (void*)p;
    p += (bytes + 255) & ~(size_t)255;
    return r;
  };
  int* deg    = (int*)alloc((size_t)N * 4);
  int* cursor = (int*)alloc((size_t)N * 4);
  char* zero_end = p;
  int* rp     = (int*)alloc((size_t)(N + 1) * 4);
  int* bt     = (int*)alloc(256 * 4);
  int* bo     = (int*)alloc(256 * 4);
  int* gstart = (int*)alloc((NGRAPH + 1) * 4);
  int* srcs   = (int*)alloc((size_t)E * 4);
  float* stats= (float*)alloc(256 * 4);
  float* partials = (float*)alloc((size_t)256 * 256 * 4);
  float* q    = (float*)alloc((size_t)N * HD * 4);
  uint4* kv   = (uint4*)alloc((size_t)N * 32 * 16);
  float* h    = (float*)alloc((size_t)N * HD * 4);
  float* x    = (float*)alloc((size_t)N * HD * 4);

  hipMemsetAsync(deg, 0, (size_t)(zero_end - (char*)deg), stream);

  const int NB  = (N + 255) / 256;
  const int EB  = (E + 255) / 256;
  const int NCB = (N * HD + 255) / 256;
  const int L1B = (N * 32 + 255) / 256;
  const int ATB = (N * 64 + 255) / 256;
  const float invN = 1.f / (float)N;

  // CSR build + graph bounds
  k_count  <<<EB, 256, 0, stream>>>(dst, deg, E);
  k_scan1  <<<NB, 256, 0, stream>>>(deg, rp, bt, N);
  k_scan2  <<<1, 256, 0, stream>>>(bt, bo, NB);
  k_scan3  <<<NB, 256, 0, stream>>>(rp, bo, N);
  k_scatter<<<EB, 256, 0, stream>>>(src, dst, rp, cursor, srcs, E);
  k_gbounds<<<1, 128, 0, stream>>>(batch, gstart, N);

  // layer 1
  k_layer1<<<L1B, 256, 0, stream>>>(X, Wq1,bq1, Wk1,bk1, Wv1,bv1, Ws1,bs1, q, kv, h, N);
  k_attn  <<<ATB, 256, 0, stream>>>(q, kv, h, rp, srcs, N);
  k_bnstats<<<NB, 256, 0, stream>>>(h, partials, N);
  k_bnreduce<<<1, 256, 0, stream>>>(partials, stats, NB);
  k_bnfin <<<NCB, 256, 0, stream>>>(h, x, stats, bn_g, bn_b, N, 0, invN);

  // layers 2..5
  for (int l = 0; l < 4; ++l){
    const float* Wql = Wq + (size_t)l*HD*HD;  const float* bql = bq + (size_t)l*HD;
    const float* Wkl = Wk + (size_t)l*HD*HD;  const float* bkl = bk + (size_t)l*HD;
    const float* Wvl = Wv + (size_t)l*HD*HD;  const float* bvl = bv + (size_t)l*HD;
    const float* Wsl = Ws + (size_t)l*HD*HD;  const float* bsl = bs + (size_t)l*HD;
    k_gemm<<<dim3((N + 63) / 64, 8), 256, 0, stream>>>(
        x, Wql, Wkl, Wvl, Wsl, bql, bkl, bvl, bsl, q, (unsigned*)kv, h, N);
    k_attn<<<ATB, 256, 0, stream>>>(q, kv, h, rp, srcs, N);
    k_bnstats<<<NB, 256, 0, stream>>>(h, partials, N);
    k_bnreduce<<<1, 256, 0, stream>>>(partials, stats, NB);
    k_bnfin<<<NCB, 256, 0, stream>>>(h, x, stats, bn_g + (size_t)(l+1)*HD, bn_b + (size_t)(l+1)*HD, N, 1, invN);
  }

  // pool + head
  k_pool<<<NGRAPH, 256, 0, stream>>>(x, gstart, Wr, br, (float*)d_out, N);
}

// Round 4
// 1152.916 us; speedup vs baseline: 1.6068x; 1.2692x over previous
//
#include <hip/hip_runtime.h>
#include <hip/hip_fp16.h>
#include <math.h>

#define HD 128
#define NGRAPH 64

typedef _Float16 f16x8 __attribute__((ext_vector_type(8)));
typedef float    f32x4 __attribute__((ext_vector_type(4)));

__device__ __forceinline__ float4 ld4(const float* p){ return *(const float4*)p; }
__device__ __forceinline__ unsigned h2bits(__half2 h){ return *(unsigned*)&h; }

// ---------------- CSR build ----------------
__global__ __launch_bounds__(256) void k_count(const int* __restrict__ dst, int* __restrict__ deg, int E){
  int e = blockIdx.x*256 + threadIdx.x;
  if (e < E) atomicAdd(&deg[dst[e]], 1);
}

__global__ __launch_bounds__(256) void k_scan1(const int* __restrict__ deg, int* __restrict__ rp,
                                               int* __restrict__ bt, int N){
  __shared__ int sm[256];
  int i = blockIdx.x*256 + threadIdx.x;
  int v = (i < N) ? deg[i] : 0;
  sm[threadIdx.x] = v;
  __syncthreads();
  for (int off = 1; off < 256; off <<= 1){
    int t = (threadIdx.x >= (unsigned)off) ? sm[threadIdx.x - off] : 0;
    __syncthreads();
    sm[threadIdx.x] += t;
    __syncthreads();
  }
  if (i < N) rp[i+1] = sm[threadIdx.x];
  if (threadIdx.x == 255) bt[blockIdx.x] = sm[255];
  if (blockIdx.x == 0 && threadIdx.x == 0) rp[0] = 0;
}

__global__ __launch_bounds__(256) void k_scan2(const int* __restrict__ bt, int* __restrict__ bo, int NB){
  __shared__ int sm[256];
  int t = threadIdx.x;
  int v = (t < NB) ? bt[t] : 0;
  sm[t] = v;
  __syncthreads();
  for (int off = 1; off < 256; off <<= 1){
    int u = (t >= (unsigned)off) ? sm[t - off] : 0;
    __syncthreads();
    sm[t] += u;
    __syncthreads();
  }
  if (t < NB) bo[t] = sm[t] - v;
}

__global__ __launch_bounds__(256) void k_scan3(int* __restrict__ rp, const int* __restrict__ bo, int N){
  int i = blockIdx.x*256 + threadIdx.x;
  if (i < N) rp[i+1] += bo[i >> 8];
}

__global__ __launch_bounds__(256) void k_scatter(const int* __restrict__ src, const int* __restrict__ dst,
                                                 const int* __restrict__ rp, int* __restrict__ cursor,
                                                 int* __restrict__ srcs, int E){
  int e = blockIdx.x*256 + threadIdx.x;
  if (e < E){
    int d = dst[e];
    int pos = atomicAdd(&cursor[d], 1);
    srcs[rp[d] + pos] = src[e];
  }
}

__global__ __launch_bounds__(128) void k_gbounds(const int* __restrict__ batch, int* __restrict__ gstart, int N){
  int g = threadIdx.x;
  if (g > NGRAPH) return;
  int lo = 0, hi = N;
  while (lo < hi){
    int mid = (lo + hi) >> 1;
    if (batch[mid] < g) lo = mid + 1; else hi = mid;
  }
  gstart[g] = lo;
}

// ---------------- weight prepack into B-fragment order (fp16) ----------------
// Wpack[mi][(chunk*8+nt)*64+lane] = { W[chunk*32+quad*8+j][nt*16+(lane&15)] , j=0..7 } as 8 halfs
__global__ __launch_bounds__(256) void k_wpack(
    const float* __restrict__ Wq, const float* __restrict__ Wk,
    const float* __restrict__ Wv, const float* __restrict__ Ws,
    uint4* __restrict__ Wpack){
  int idx = blockIdx.x*256 + threadIdx.x;
  if (idx >= 16*2048) return;
  int mi   = idx >> 11;
  int rem  = idx & 2047;
  int lane = rem & 63;
  int tile = rem >> 6;         // chunk*8+nt
  int chunk = tile >> 3, nt = tile & 7;
  int l = mi >> 2, ws = mi & 3;
  const float* W = (ws==0?Wq:ws==1?Wk:ws==2?Wv:Ws) + (size_t)l*HD*HD;
  int quad = lane >> 4;
  int n = nt*16 + (lane & 15);
  int k0 = chunk*32 + quad*8;
  __half hs[8];
  #pragma unroll
  for (int j = 0; j < 8; ++j) hs[j] = __float2half(W[(size_t)(k0+j)*HD + n]);
  Wpack[idx] = *(uint4*)hs;
}

// ---------------- layer 1 projection (in_dim = 1) ----------------
__global__ __launch_bounds__(256) void k_layer1(
    const float* __restrict__ X,
    const float* __restrict__ Wq1, const float* __restrict__ bq1,
    const float* __restrict__ Wk1, const float* __restrict__ bk1,
    const float* __restrict__ Wv1, const float* __restrict__ bv1,
    const float* __restrict__ Ws1, const float* __restrict__ bs1,
    float* __restrict__ q, uint4* __restrict__ kv, float* __restrict__ h, int N){
  int idx = blockIdx.x*256 + threadIdx.x;
  if (idx >= N*32) return;
  int n = idx >> 5, s4 = idx & 31, c = s4 << 2;
  float xv = X[n];
  float qv[4], kk[4], vv[4], hv[4];
  #pragma unroll
  for (int i = 0; i < 4; ++i){
    qv[i] = xv*Wq1[c+i] + bq1[c+i];
    kk[i] = xv*Wk1[c+i] + bk1[c+i];
    vv[i] = xv*Wv1[c+i] + bv1[c+i];
    hv[i] = xv*Ws1[c+i] + bs1[c+i];
  }
  *(float4*)(q + (size_t)n*HD + c) = make_float4(qv[0],qv[1],qv[2],qv[3]);
  *(float4*)(h + (size_t)n*HD + c) = make_float4(hv[0],hv[1],hv[2],hv[3]);
  uint4 g;
  g.x = h2bits(__floats2half2_rn(kk[0], kk[1]));
  g.y = h2bits(__floats2half2_rn(kk[2], kk[3]));
  g.z = h2bits(__floats2half2_rn(vv[0], vv[1]));
  g.w = h2bits(__floats2half2_rn(vv[2], vv[3]));
  kv[(size_t)n*32 + s4] = g;
}

// ---------------- MFMA QKVS GEMM ----------------
// grid = (ceil(N/64), 4): blockIdx.y = wsel {q,k,v,h}. 4 waves; wave w: rows [64b + 16w, +16)
__global__ __launch_bounds__(256) void k_gemm(
    const __half* __restrict__ xh, const uint4* __restrict__ Wpack,
    const float* __restrict__ bq, const float* __restrict__ bk,
    const float* __restrict__ bv, const float* __restrict__ bs,
    float* __restrict__ q, unsigned* __restrict__ kvbuf, float* __restrict__ h,
    int N, int layer){
  __shared__ uint4 Bs[2048];   // 32 KB: full Wpack for this matrix
  int wsel = blockIdx.y;
  const uint4* Wm = Wpack + (size_t)(layer*4 + wsel)*2048;
  int tid = threadIdx.x;
  for (int i = tid; i < 2048; i += 256) Bs[i] = Wm[i];

  int w = tid >> 6, lane = tid & 63;
  int l15 = lane & 15, quad = lane >> 4;
  int row0 = blockIdx.x*64 + w*16;
  int arow = row0 + l15;
  const float* bias = (wsel==0)?bq:(wsel==1)?bk:(wsel==2)?bv:bs;

  f32x4 acc[8];
  #pragma unroll
  for (int i = 0; i < 8; ++i) acc[i] = (f32x4){0.f,0.f,0.f,0.f};

  __syncthreads();

  #pragma unroll
  for (int chunk = 0; chunk < 4; ++chunk){
    f16x8 a = {};
    if (arow < N) a = *(const f16x8*)(xh + (size_t)arow*HD + chunk*32 + quad*8);
    #pragma unroll
    for (int nt = 0; nt < 8; ++nt){
      f16x8 b = *(const f16x8*)&Bs[(chunk*8 + nt)*64 + lane];
      acc[nt] = __builtin_amdgcn_mfma_f32_16x16x32_f16(a, b, acc[nt], 0, 0, 0);
    }
  }

  // epilogue: D layout col=lane&15, row=quad*4+reg
  if (wsel == 0 || wsel == 3){
    float* out = (wsel == 0) ? q : h;
    #pragma unroll
    for (int nt = 0; nt < 8; ++nt){
      int col = nt*16 + l15;
      float b = bias[col];
      #pragma unroll
      for (int reg = 0; reg < 4; ++reg){
        int row = row0 + quad*4 + reg;
        if (row < N) out[(size_t)row*HD + col] = acc[nt][reg] + b;
      }
    }
  } else {
    int voff = (wsel == 2) ? 2 : 0;
    #pragma unroll
    for (int nt = 0; nt < 8; ++nt){
      int col = nt*16 + l15;
      float b = bias[col];
      int widx = ((col >> 2) << 2) + ((col >> 1) & 1) + voff;
      #pragma unroll
      for (int reg = 0; reg < 4; ++reg){
        float val = acc[nt][reg] + b;
        float oth = __shfl_xor(val, 1);   // neighbor column (col^1)
        int row = row0 + quad*4 + reg;
        if (!(l15 & 1) && row < N)
          kvbuf[(size_t)row*HD + widx] = h2bits(__floats2half2_rn(val, oth));
      }
    }
  }
}

// ---------------- attention: one wave per dst node, 2 edges per iteration ----------------
__global__ __launch_bounds__(256) void k_attn(
    const float* __restrict__ q, const uint4* __restrict__ kv,
    float* __restrict__ h, const int* __restrict__ rp, const int* __restrict__ srcs, int N){
  int wid = (blockIdx.x*256 + threadIdx.x) >> 6;
  if (wid >= N) return;
  int lane = threadIdx.x & 63;
  int half = lane >> 5, l5 = lane & 31;
  int n = wid;
  float4 qv = *(const float4*)(q + (size_t)n*HD + (l5 << 2));
  int beg = rp[n], end = rp[n+1];

  float m = -INFINITY, lsum = 0.f;
  float a0 = 0.f, a1 = 0.f, a2 = 0.f, a3 = 0.f;

  auto upd = [&](uint4 g, bool valid){
    float2 k01 = __half22float2(*(const __half2*)&g.x);
    float2 k23 = __half22float2(*(const __half2*)&g.y);
    float2 v01 = __half22float2(*(const __half2*)&g.z);
    float2 v23 = __half22float2(*(const __half2*)&g.w);
    float pd = qv.x*k01.x + qv.y*k01.y + qv.z*k23.x + qv.w*k23.y;
    pd += __shfl_xor(pd, 1);
    pd += __shfl_xor(pd, 2);
    if (valid){
      float alpha = pd * 0.25f;
      float mn = fmaxf(m, alpha);
      float sc = __expf(m - mn);
      float e  = __expf(alpha - mn);
      lsum = lsum*sc + e;
      a0 = a0*sc + e*v01.x;
      a1 = a1*sc + e*v01.y;
      a2 = a2*sc + e*v23.x;
      a3 = a3*sc + e*v23.y;
      m = mn;
    }
  };

  for (int cb = beg; cb < end; cb += 64){
    int cnt = min(64, end - cb);
    int s_pre = (cb + lane < end) ? srcs[cb + lane] : 0;
    int npair = (cnt + 1) >> 1;
    int t = 0;
    for (; t + 2 <= npair; t += 2){
      int e0 = 2*t + half, e1 = e0 + 2;
      int s0 = __shfl(s_pre, e0);
      int s1 = __shfl(s_pre, e1);
      uint4 g0 = kv[(size_t)s0*32 + l5];
      uint4 g1 = kv[(size_t)s1*32 + l5];
      upd(g0, e0 < cnt);
      upd(g1, e1 < cnt);
    }
    for (; t < npair; ++t){
      int e0 = 2*t + half;
      int s0 = __shfl(s_pre, e0);
      uint4 g0 = kv[(size_t)s0*32 + l5];
      upd(g0, e0 < cnt);
    }
  }

  float m_o  = __shfl_xor(m, 32);
  float l_o  = __shfl_xor(lsum, 32);
  float x0 = __shfl_xor(a0, 32);
  float x1 = __shfl_xor(a1, 32);
  float x2 = __shfl_xor(a2, 32);
  float x3 = __shfl_xor(a3, 32);
  float mn = fmaxf(m, m_o);
  float sc_s = (m   > -INFINITY) ? __expf(m   - mn) : 0.f;
  float sc_o = (m_o > -INFINITY) ? __expf(m_o - mn) : 0.f;
  lsum = lsum*sc_s + l_o*sc_o;
  a0 = a0*sc_s + x0*sc_o;
  a1 = a1*sc_s + x1*sc_o;
  a2 = a2*sc_s + x2*sc_o;
  a3 = a3*sc_s + x3*sc_o;
  float inv = (lsum > 0.f) ? 1.f/lsum : 0.f;

  if (half == 0){
    float4 skip = *(const float4*)(h + (size_t)n*HD + (l5 << 2));
    float4 o;
    o.x = fmaxf(a0*inv + skip.x, 0.f);
    o.y = fmaxf(a1*inv + skip.y, 0.f);
    o.z = fmaxf(a2*inv + skip.z, 0.f);
    o.w = fmaxf(a3*inv + skip.w, 0.f);
    *(float4*)(h + (size_t)n*HD + (l5 << 2)) = o;
  }
}

// ---------------- BN stats ----------------
__global__ __launch_bounds__(256) void k_bnstats(const float* __restrict__ h, float* __restrict__ partials, int N){
  __shared__ float sm[512];
  int t = threadIdx.x;
  int c = t & 127, half = t >> 7;
  int r0 = blockIdx.x * 256;
  int rend = min(r0 + 256, N);
  float s = 0.f, sq = 0.f;
  for (int r = r0 + half; r < rend; r += 2){
    float val = h[(size_t)r*HD + c];
    s += val; sq += val*val;
  }
  sm[t] = s; sm[256 + t] = sq;
  __syncthreads();
  if (t < 128){
    partials[(size_t)blockIdx.x*256 + t]       = sm[t] + sm[t + 128];
    partials[(size_t)blockIdx.x*256 + 128 + t] = sm[256 + t] + sm[256 + t + 128];
  }
}

__global__ __launch_bounds__(256) void k_bnreduce(const float* __restrict__ partials,
                                                  float* __restrict__ stats, int NB){
  int t = threadIdx.x;
  float s = 0.f;
  for (int b = 0; b < NB; ++b) s += partials[(size_t)b*256 + t];
  stats[t] = s;
}

// ---------------- BN finalize (+ residual) ; also emit fp16 copy of x ----------------
__global__ __launch_bounds__(256) void k_bnfin(
    const float* __restrict__ h, float* __restrict__ x, __half* __restrict__ xh,
    const float* __restrict__ stats,
    const float* __restrict__ gamma, const float* __restrict__ beta, int N, int resid, float invN){
  int idx = blockIdx.x*256 + threadIdx.x;
  if (idx >= N*HD) return;
  int c = idx & 127;
  float mu  = stats[c] * invN;
  float var = stats[128 + c] * invN - mu*mu;
  float scl = rsqrtf(var + 1e-5f) * gamma[c];
  float o = (h[idx] - mu) * scl + beta[c];
  float xn = resid ? (x[idx] + o) : o;
  x[idx]  = xn;
  xh[idx] = __float2half(xn);
}

// ---------------- pool stage 1: per (graph, chunk) partial sums ----------------
__global__ __launch_bounds__(256) void k_pool1(
    const float* __restrict__ x, const int* __restrict__ gstart,
    float* __restrict__ pp, int N){
  __shared__ float sm[256];
  int g = blockIdx.x, chunk = blockIdx.y;
  int t = threadIdx.x;
  int c = t & 127, half = t >> 7;
  int start = gstart[g];
  int endr  = gstart[g+1];
  float s = 0.f;
  for (int r = start + chunk*2 + half; r < endr; r += 16) s += x[(size_t)r*HD + c];
  sm[t] = s;
  __syncthreads();
  if (t < 128) pp[(size_t)(g*8 + chunk)*128 + t] = sm[t] + sm[t + 128];
}

// ---------------- pool stage 2: reduce chunks, mean, regression head ----------------
__global__ __launch_bounds__(128) void k_pool2(
    const float* __restrict__ pp, const int* __restrict__ gstart,
    const float* __restrict__ Wr, const float* __restrict__ br,
    float* __restrict__ out){
  __shared__ float sm[128];
  int g = blockIdx.x, c = threadIdx.x;
  float s = 0.f;
  #pragma unroll
  for (int j = 0; j < 8; ++j) s += pp[(size_t)(g*8 + j)*128 + c];
  int cnt = gstart[g+1] - gstart[g];
  float xm = s / fmaxf((float)cnt, 1.f);
  out[NGRAPH + g*HD + c] = xm;
  sm[c] = xm * Wr[c];
  __syncthreads();
  for (int off = 64; off > 0; off >>= 1){
    if (c < off) sm[c] += sm[c + off];
    __syncthreads();
  }
  if (c == 0) out[g] = sm[0] + br[0];
}

extern "C" void kernel_launch(void* const* d_in, const int* in_sizes, int n_in,
                              void* d_out, int out_size, void* d_ws, size_t ws_size,
                              hipStream_t stream){
  const float* X     = (const float*)d_in[0];
  const int*   ei    = (const int*)  d_in[1];
  const int*   batch = (const int*)  d_in[2];
  const float* Wq1 = (const float*)d_in[3];  const float* bq1 = (const float*)d_in[4];
  const float* Wk1 = (const float*)d_in[5];  const float* bk1 = (const float*)d_in[6];
  const float* Wv1 = (const float*)d_in[7];  const float* bv1 = (const float*)d_in[8];
  const float* Ws1 = (const float*)d_in[9];  const float* bs1 = (const float*)d_in[10];
  const float* Wq  = (const float*)d_in[11]; const float* bq  = (const float*)d_in[12];
  const float* Wk  = (const float*)d_in[13]; const float* bk  = (const float*)d_in[14];
  const float* Wv  = (const float*)d_in[15]; const float* bv  = (const float*)d_in[16];
  const float* Ws  = (const float*)d_in[17]; const float* bs  = (const float*)d_in[18];
  const float* bn_g= (const float*)d_in[19]; const float* bn_b= (const float*)d_in[20];
  const float* Wr  = (const float*)d_in[21]; const float* br  = (const float*)d_in[22];

  const int N = in_sizes[0];
  const int E = in_sizes[1] / 2;

  const int* src = ei;
  const int* dst = ei + E;

  char* p = (char*)d_ws;
  auto alloc = [&](size_t bytes) -> void* {
    void* r = (void*)p;
    p += (bytes + 255) & ~(size_t)255;
    return r;
  };
  int* deg    = (int*)alloc((size_t)N * 4);
  int* cursor = (int*)alloc((size_t)N * 4);
  char* zero_end = p;
  int* rp     = (int*)alloc((size_t)(N + 1) * 4);
  int* bt     = (int*)alloc(256 * 4);
  int* bo     = (int*)alloc(256 * 4);
  int* gstart = (int*)alloc((NGRAPH + 1) * 4);
  int* srcs   = (int*)alloc((size_t)E * 4);
  float* stats= (float*)alloc(256 * 4);
  float* partials = (float*)alloc((size_t)256 * 256 * 4);
  float* pp   = (float*)alloc((size_t)NGRAPH * 8 * 128 * 4);
  uint4* Wpack= (uint4*)alloc((size_t)16 * 2048 * 16);
  float* q    = (float*)alloc((size_t)N * HD * 4);
  uint4* kv   = (uint4*)alloc((size_t)N * 32 * 16);
  float* h    = (float*)alloc((size_t)N * HD * 4);
  float* x    = (float*)alloc((size_t)N * HD * 4);
  __half* xh  = (__half*)alloc((size_t)N * HD * 2);

  hipMemsetAsync(deg, 0, (size_t)(zero_end - (char*)deg), stream);

  const int NB  = (N + 255) / 256;
  const int EB  = (E + 255) / 256;
  const int NCB = (N * HD + 255) / 256;
  const int L1B = (N * 32 + 255) / 256;
  const int ATB = (N * 64 + 255) / 256;
  const float invN = 1.f / (float)N;

  // CSR build + graph bounds + weight prepack
  k_count  <<<EB, 256, 0, stream>>>(dst, deg, E);
  k_scan1  <<<NB, 256, 0, stream>>>(deg, rp, bt, N);
  k_scan2  <<<1, 256, 0, stream>>>(bt, bo, NB);
  k_scan3  <<<NB, 256, 0, stream>>>(rp, bo, N);
  k_scatter<<<EB, 256, 0, stream>>>(src, dst, rp, cursor, srcs, E);
  k_gbounds<<<1, 128, 0, stream>>>(batch, gstart, N);
  k_wpack  <<<128, 256, 0, stream>>>(Wq, Wk, Wv, Ws, Wpack);

  // layer 1
  k_layer1<<<L1B, 256, 0, stream>>>(X, Wq1,bq1, Wk1,bk1, Wv1,bv1, Ws1,bs1, q, kv, h, N);
  k_attn  <<<ATB, 256, 0, stream>>>(q, kv, h, rp, srcs, N);
  k_bnstats<<<NB, 256, 0, stream>>>(h, partials, N);
  k_bnreduce<<<1, 256, 0, stream>>>(partials, stats, NB);
  k_bnfin <<<NCB, 256, 0, stream>>>(h, x, xh, stats, bn_g, bn_b, N, 0, invN);

  // layers 2..5 (MFMA GEMM)
  for (int l = 0; l < 4; ++l){
    k_gemm<<<dim3((N + 63) / 64, 4), 256, 0, stream>>>(
        xh, Wpack, bq + (size_t)l*HD, bk + (size_t)l*HD, bv + (size_t)l*HD, bs + (size_t)l*HD,
        q, (unsigned*)kv, h, N, l);
    k_attn<<<ATB, 256, 0, stream>>>(q, kv, h, rp, srcs, N);
    k_bnstats<<<NB, 256, 0, stream>>>(h, partials, N);
    k_bnreduce<<<1, 256, 0, stream>>>(partials, stats, NB);
    k_bnfin<<<NCB, 256, 0, stream>>>(h, x, xh, stats, bn_g + (size_t)(l+1)*HD, bn_b + (size_t)(l+1)*HD, N, 1, invN);
  }

  // pool + head
  k_pool1<<<dim3(NGRAPH, 8), 256, 0, stream>>>(x, gstart, pp, N);
  k_pool2<<<NGRAPH, 128, 0, stream>>>(pp, gstart, Wr, br, (float*)d_out);
}

// Round 5
// 1076.267 us; speedup vs baseline: 1.7212x; 1.0712x over previous
//
#include <hip/hip_runtime.h>
#include <hip/hip_fp16.h>
#include <math.h>

#define HD 128
#define NGRAPH 64

typedef _Float16 f16x8 __attribute__((ext_vector_type(8)));
typedef _Float16 f16x2 __attribute__((ext_vector_type(2)));
typedef float    f32x4 __attribute__((ext_vector_type(4)));

__device__ __forceinline__ float4 ld4(const float* p){ return *(const float4*)p; }
__device__ __forceinline__ unsigned h2bits(__half2 h){ return *(unsigned*)&h; }

__device__ __forceinline__ float fdot2u(unsigned a, unsigned b, float c){
#if __has_builtin(__builtin_amdgcn_fdot2)
  return __builtin_amdgcn_fdot2(*(f16x2*)&a, *(f16x2*)&b, c, false);
#else
  float2 fa = __half22float2(*(__half2*)&a);
  float2 fb = __half22float2(*(__half2*)&b);
  return c + fa.x*fb.x + fa.y*fb.y;
#endif
}

// ---------------- CSR build ----------------
__global__ __launch_bounds__(256) void k_count(const int* __restrict__ dst, int* __restrict__ deg, int E){
  int e = blockIdx.x*256 + threadIdx.x;
  if (e < E) atomicAdd(&deg[dst[e]], 1);
}

__global__ __launch_bounds__(256) void k_scan1(const int* __restrict__ deg, int* __restrict__ rp,
                                               int* __restrict__ bt, int N){
  __shared__ int sm[256];
  int i = blockIdx.x*256 + threadIdx.x;
  int v = (i < N) ? deg[i] : 0;
  sm[threadIdx.x] = v;
  __syncthreads();
  for (int off = 1; off < 256; off <<= 1){
    int t = (threadIdx.x >= (unsigned)off) ? sm[threadIdx.x - off] : 0;
    __syncthreads();
    sm[threadIdx.x] += t;
    __syncthreads();
  }
  if (i < N) rp[i+1] = sm[threadIdx.x];
  if (threadIdx.x == 255) bt[blockIdx.x] = sm[255];
  if (blockIdx.x == 0 && threadIdx.x == 0) rp[0] = 0;
}

__global__ __launch_bounds__(256) void k_scan2(const int* __restrict__ bt, int* __restrict__ bo, int NB){
  __shared__ int sm[256];
  int t = threadIdx.x;
  int v = (t < NB) ? bt[t] : 0;
  sm[t] = v;
  __syncthreads();
  for (int off = 1; off < 256; off <<= 1){
    int u = (t >= (unsigned)off) ? sm[t - off] : 0;
    __syncthreads();
    sm[t] += u;
    __syncthreads();
  }
  if (t < NB) bo[t] = sm[t] - v;
}

__global__ __launch_bounds__(256) void k_scan3(int* __restrict__ rp, const int* __restrict__ bo, int N){
  int i = blockIdx.x*256 + threadIdx.x;
  if (i < N) rp[i+1] += bo[i >> 8];
}

__global__ __launch_bounds__(256) void k_scatter(const int* __restrict__ src, const int* __restrict__ dst,
                                                 const int* __restrict__ rp, int* __restrict__ cursor,
                                                 int* __restrict__ srcs, int E){
  int e = blockIdx.x*256 + threadIdx.x;
  if (e < E){
    int d = dst[e];
    int pos = atomicAdd(&cursor[d], 1);
    srcs[rp[d] + pos] = src[e];
  }
}

__global__ __launch_bounds__(128) void k_gbounds(const int* __restrict__ batch, int* __restrict__ gstart, int N){
  int g = threadIdx.x;
  if (g > NGRAPH) return;
  int lo = 0, hi = N;
  while (lo < hi){
    int mid = (lo + hi) >> 1;
    if (batch[mid] < g) lo = mid + 1; else hi = mid;
  }
  gstart[g] = lo;
}

// ---------------- weight prepack into B-fragment order (fp16) ----------------
__global__ __launch_bounds__(256) void k_wpack(
    const float* __restrict__ Wq, const float* __restrict__ Wk,
    const float* __restrict__ Wv, const float* __restrict__ Ws,
    uint4* __restrict__ Wpack){
  int idx = blockIdx.x*256 + threadIdx.x;
  if (idx >= 16*2048) return;
  int mi   = idx >> 11;
  int rem  = idx & 2047;
  int lane = rem & 63;
  int tile = rem >> 6;
  int chunk = tile >> 3, nt = tile & 7;
  int l = mi >> 2, ws = mi & 3;
  const float* W = (ws==0?Wq:ws==1?Wk:ws==2?Wv:Ws) + (size_t)l*HD*HD;
  int quad = lane >> 4;
  int n = nt*16 + (lane & 15);
  int k0 = chunk*32 + quad*8;
  __half hs[8];
  #pragma unroll
  for (int j = 0; j < 8; ++j) hs[j] = __float2half(W[(size_t)(k0+j)*HD + n]);
  Wpack[idx] = *(uint4*)hs;
}

// ---------------- layer 1 projection (in_dim = 1) ----------------
// qh: fp16 [node][128] (head-major = natural order); kvh: per node 8 heads x {k16,v16} fp16
__global__ __launch_bounds__(256) void k_layer1(
    const float* __restrict__ X,
    const float* __restrict__ Wq1, const float* __restrict__ bq1,
    const float* __restrict__ Wk1, const float* __restrict__ bk1,
    const float* __restrict__ Wv1, const float* __restrict__ bv1,
    const float* __restrict__ Ws1, const float* __restrict__ bs1,
    unsigned* __restrict__ qh_u, unsigned* __restrict__ kvh_u, float* __restrict__ h, int N){
  int idx = blockIdx.x*256 + threadIdx.x;
  if (idx >= N*32) return;
  int n = idx >> 5, s4 = idx & 31, c = s4 << 2;
  float xv = X[n];
  float qv[4], kk[4], vv[4], hv[4];
  #pragma unroll
  for (int i = 0; i < 4; ++i){
    qv[i] = xv*Wq1[c+i] + bq1[c+i];
    kk[i] = xv*Wk1[c+i] + bk1[c+i];
    vv[i] = xv*Wv1[c+i] + bv1[c+i];
    hv[i] = xv*Ws1[c+i] + bs1[c+i];
  }
  *(float4*)(h + (size_t)n*HD + c) = make_float4(hv[0],hv[1],hv[2],hv[3]);
  uint2 qw;
  qw.x = h2bits(__floats2half2_rn(qv[0], qv[1]));
  qw.y = h2bits(__floats2half2_rn(qv[2], qv[3]));
  *(uint2*)&qh_u[(size_t)n*64 + (c >> 1)] = qw;
  int head = c >> 4, ch = c & 15;
  size_t kbase = (size_t)n*128 + head*16 + (ch >> 1);
  uint2 kw, vw;
  kw.x = h2bits(__floats2half2_rn(kk[0], kk[1]));
  kw.y = h2bits(__floats2half2_rn(kk[2], kk[3]));
  vw.x = h2bits(__floats2half2_rn(vv[0], vv[1]));
  vw.y = h2bits(__floats2half2_rn(vv[2], vv[3]));
  *(uint2*)&kvh_u[kbase]     = kw;
  *(uint2*)&kvh_u[kbase + 8] = vw;
}

// ---------------- MFMA QKVS GEMM ----------------
// grid = (ceil(N/64), 4): blockIdx.y = wsel {q,k,v,h}
__global__ __launch_bounds__(256) void k_gemm(
    const __half* __restrict__ xh, const uint4* __restrict__ Wpack,
    const float* __restrict__ bq, const float* __restrict__ bk,
    const float* __restrict__ bv, const float* __restrict__ bs,
    unsigned* __restrict__ qh_u, unsigned* __restrict__ kvh_u, float* __restrict__ h,
    int N, int layer){
  __shared__ uint4 Bs[2048];
  int wsel = blockIdx.y;
  const uint4* Wm = Wpack + (size_t)(layer*4 + wsel)*2048;
  int tid = threadIdx.x;
  for (int i = tid; i < 2048; i += 256) Bs[i] = Wm[i];

  int w = tid >> 6, lane = tid & 63;
  int l15 = lane & 15, quad = lane >> 4;
  int row0 = blockIdx.x*64 + w*16;
  int arow = row0 + l15;
  const float* bias = (wsel==0)?bq:(wsel==1)?bk:(wsel==2)?bv:bs;

  f32x4 acc[8];
  #pragma unroll
  for (int i = 0; i < 8; ++i) acc[i] = (f32x4){0.f,0.f,0.f,0.f};

  __syncthreads();

  #pragma unroll
  for (int chunk = 0; chunk < 4; ++chunk){
    f16x8 a = {};
    if (arow < N) a = *(const f16x8*)(xh + (size_t)arow*HD + chunk*32 + quad*8);
    #pragma unroll
    for (int nt = 0; nt < 8; ++nt){
      f16x8 b = *(const f16x8*)&Bs[(chunk*8 + nt)*64 + lane];
      acc[nt] = __builtin_amdgcn_mfma_f32_16x16x32_f16(a, b, acc[nt], 0, 0, 0);
    }
  }

  // D layout: col = nt*16 + l15, row = row0 + quad*4 + reg
  if (wsel == 3){
    #pragma unroll
    for (int nt = 0; nt < 8; ++nt){
      int col = nt*16 + l15;
      float b = bias[col];
      #pragma unroll
      for (int reg = 0; reg < 4; ++reg){
        int row = row0 + quad*4 + reg;
        if (row < N) h[(size_t)row*HD + col] = acc[nt][reg] + b;
      }
    }
  } else {
    #pragma unroll
    for (int nt = 0; nt < 8; ++nt){
      int col = nt*16 + l15;
      float b = bias[col];
      #pragma unroll
      for (int reg = 0; reg < 4; ++reg){
        float val = acc[nt][reg] + b;
        float oth = __shfl_xor(val, 1);
        int row = row0 + quad*4 + reg;
        if (!(l15 & 1) && row < N){
          unsigned pk = h2bits(__floats2half2_rn(val, oth));
          if (wsel == 0)       qh_u[(size_t)row*64  + nt*8  + (l15>>1)]      = pk;
          else if (wsel == 1)  kvh_u[(size_t)row*128 + nt*16 + (l15>>1)]     = pk;
          else                 kvh_u[(size_t)row*128 + nt*16 + (l15>>1) + 8] = pk;
        }
      }
    }
  }
}

// ---------------- attention: wave per node; lane = (edge-slot, head); plain-exp softmax ----------------
// Also emits per-block BN partials (sum, sumsq).
__global__ __launch_bounds__(256) void k_attn(
    const uint4* __restrict__ qh4, const uint4* __restrict__ kvh4,
    float* __restrict__ h, float* __restrict__ partials,
    const int* __restrict__ rp, const int* __restrict__ srcs, int N){
  __shared__ float ssum[4][128];
  __shared__ float ssq[4][128];
  int tid = threadIdx.x;
  int w = tid >> 6, lane = tid & 63;
  int oct = lane >> 3, hh = lane & 7;
  int n = blockIdx.x*4 + w;
  bool active = (n < N);

  float acc[16];
  #pragma unroll
  for (int i = 0; i < 16; ++i) acc[i] = 0.f;
  float lsum = 0.f;

  if (active){
    uint4 q0 = qh4[(size_t)n*16 + hh*2];
    uint4 q1 = qh4[(size_t)n*16 + hh*2 + 1];
    unsigned qr[8] = {q0.x,q0.y,q0.z,q0.w, q1.x,q1.y,q1.z,q1.w};
    int beg = rp[n], end = rp[n+1];
    for (int t = beg + oct; t < end; t += 8){
      int s = srcs[t];
      const uint4* base = kvh4 + (size_t)s*32 + hh*4;
      uint4 g0 = base[0];
      uint4 g1 = base[1];
      uint4 g2 = base[2];
      uint4 g3 = base[3];
      unsigned kr[8] = {g0.x,g0.y,g0.z,g0.w, g1.x,g1.y,g1.z,g1.w};
      float pd = 0.f;
      #pragma unroll
      for (int i = 0; i < 8; ++i) pd = fdot2u(kr[i], qr[i], pd);
      float e = __expf(pd * 0.25f);      // no max-subtract: |alpha| bounded by BN-normalized activations
      lsum += e;
      unsigned vr[8] = {g2.x,g2.y,g2.z,g2.w, g3.x,g3.y,g3.z,g3.w};
      #pragma unroll
      for (int i = 0; i < 8; ++i){
        float2 vf = __half22float2(*(__half2*)&vr[i]);
        acc[2*i]   += e*vf.x;
        acc[2*i+1] += e*vf.y;
      }
    }
  }

  // merge 8 edge-slot streams (lanes with equal head): xor 8,16,32
  #pragma unroll
  for (int mask = 8; mask <= 32; mask <<= 1){
    lsum += __shfl_xor(lsum, mask);
    #pragma unroll
    for (int i = 0; i < 16; ++i) acc[i] += __shfl_xor(acc[i], mask);
  }
  float inv = (lsum > 0.f) ? 1.f/lsum : 0.f;

  float out[16];
  #pragma unroll
  for (int i = 0; i < 16; ++i) out[i] = 0.f;
  if (active && oct == 0){
    float4* hp = (float4*)(h + (size_t)n*HD + hh*16);
    #pragma unroll
    for (int j = 0; j < 4; ++j){
      float4 sk = hp[j];
      out[4*j+0] = fmaxf(acc[4*j+0]*inv + sk.x, 0.f);
      out[4*j+1] = fmaxf(acc[4*j+1]*inv + sk.y, 0.f);
      out[4*j+2] = fmaxf(acc[4*j+2]*inv + sk.z, 0.f);
      out[4*j+3] = fmaxf(acc[4*j+3]*inv + sk.w, 0.f);
      hp[j] = make_float4(out[4*j+0], out[4*j+1], out[4*j+2], out[4*j+3]);
    }
  }
  if (oct == 0){
    #pragma unroll
    for (int j = 0; j < 16; ++j){
      int c = hh*16 + j;
      ssum[w][c] = out[j];
      ssq[w][c]  = out[j]*out[j];
    }
  }
  __syncthreads();
  if (tid < 128){
    partials[(size_t)blockIdx.x*256 + tid] = ssum[0][tid]+ssum[1][tid]+ssum[2][tid]+ssum[3][tid];
  } else {
    int c = tid - 128;
    partials[(size_t)blockIdx.x*256 + tid] = ssq[0][c]+ssq[1][c]+ssq[2][c]+ssq[3][c];
  }
}

// ---------------- BN reduce level 1: NBLK rows -> nred rows ----------------
__global__ __launch_bounds__(256) void k_red1(const float* __restrict__ partials,
                                               float* __restrict__ pr2, int NBLK){
  int t = threadIdx.x, b = blockIdx.x;
  int r0 = b*128, r1 = min(r0 + 128, NBLK);
  float s = 0.f;
  for (int r = r0; r < r1; ++r) s += partials[(size_t)r*256 + t];
  pr2[(size_t)b*256 + t] = s;
}

// ---------------- BN finalize: redundant stats reduce + normalize (+residual), emit xh ----------------
__global__ __launch_bounds__(256) void k_bnfin(
    const float* __restrict__ h, float* __restrict__ x, __half* __restrict__ xh,
    const float* __restrict__ pr2, int nred,
    const float* __restrict__ gamma, const float* __restrict__ beta,
    int N, int resid, float invN){
  int t = threadIdx.x;
  int c = t & 127;
  float s = 0.f, sq = 0.f;
  for (int i = 0; i < nred; ++i){
    s  += pr2[(size_t)i*256 + c];
    sq += pr2[(size_t)i*256 + 128 + c];
  }
  float mu  = s * invN;
  float var = sq * invN - mu*mu;
  float scl = rsqrtf(var + 1e-5f) * gamma[c];
  float bb  = beta[c] - mu*scl;
  int rend = min(blockIdx.x*64 + 64, N);
  for (int r = blockIdx.x*64 + (t >> 7); r < rend; r += 2){
    size_t idx = (size_t)r*HD + c;
    float o = h[idx]*scl + bb;
    float xn = resid ? (x[idx] + o) : o;
    x[idx]  = xn;
    xh[idx] = __float2half(xn);
  }
}

// ---------------- pool stage 1 ----------------
__global__ __launch_bounds__(256) void k_pool1(
    const float* __restrict__ x, const int* __restrict__ gstart,
    float* __restrict__ pp, int N){
  __shared__ float sm[256];
  int g = blockIdx.x, chunk = blockIdx.y;
  int t = threadIdx.x;
  int c = t & 127, half = t >> 7;
  int start = gstart[g];
  int endr  = gstart[g+1];
  float s = 0.f;
  for (int r = start + chunk*2 + half; r < endr; r += 16) s += x[(size_t)r*HD + c];
  sm[t] = s;
  __syncthreads();
  if (t < 128) pp[(size_t)(g*8 + chunk)*128 + t] = sm[t] + sm[t + 128];
}

// ---------------- pool stage 2 ----------------
__global__ __launch_bounds__(128) void k_pool2(
    const float* __restrict__ pp, const int* __restrict__ gstart,
    const float* __restrict__ Wr, const float* __restrict__ br,
    float* __restrict__ out){
  __shared__ float sm[128];
  int g = blockIdx.x, c = threadIdx.x;
  float s = 0.f;
  #pragma unroll
  for (int j = 0; j < 8; ++j) s += pp[(size_t)(g*8 + j)*128 + c];
  int cnt = gstart[g+1] - gstart[g];
  float xm = s / fmaxf((float)cnt, 1.f);
  out[NGRAPH + g*HD + c] = xm;
  sm[c] = xm * Wr[c];
  __syncthreads();
  for (int off = 64; off > 0; off >>= 1){
    if (c < off) sm[c] += sm[c + off];
    __syncthreads();
  }
  if (c == 0) out[g] = sm[0] + br[0];
}

extern "C" void kernel_launch(void* const* d_in, const int* in_sizes, int n_in,
                              void* d_out, int out_size, void* d_ws, size_t ws_size,
                              hipStream_t stream){
  const float* X     = (const float*)d_in[0];
  const int*   ei    = (const int*)  d_in[1];
  const int*   batch = (const int*)  d_in[2];
  const float* Wq1 = (const float*)d_in[3];  const float* bq1 = (const float*)d_in[4];
  const float* Wk1 = (const float*)d_in[5];  const float* bk1 = (const float*)d_in[6];
  const float* Wv1 = (const float*)d_in[7];  const float* bv1 = (const float*)d_in[8];
  const float* Ws1 = (const float*)d_in[9];  const float* bs1 = (const float*)d_in[10];
  const float* Wq  = (const float*)d_in[11]; const float* bq  = (const float*)d_in[12];
  const float* Wk  = (const float*)d_in[13]; const float* bk  = (const float*)d_in[14];
  const float* Wv  = (const float*)d_in[15]; const float* bv  = (const float*)d_in[16];
  const float* Ws  = (const float*)d_in[17]; const float* bs  = (const float*)d_in[18];
  const float* bn_g= (const float*)d_in[19]; const float* bn_b= (const float*)d_in[20];
  const float* Wr  = (const float*)d_in[21]; const float* br  = (const float*)d_in[22];

  const int N = in_sizes[0];
  const int E = in_sizes[1] / 2;

  const int* src = ei;
  const int* dst = ei + E;

  char* p = (char*)d_ws;
  auto alloc = [&](size_t bytes) -> void* {
    void* r = (void*)p;
    p += (bytes + 255) & ~(size_t)255;
    return r;
  };
  int* deg    = (int*)alloc((size_t)N * 4);
  int* cursor = (int*)alloc((size_t)N * 4);
  char* zero_end = p;
  int* rp     = (int*)alloc((size_t)(N + 1) * 4);
  int* bt     = (int*)alloc(256 * 4);
  int* bo     = (int*)alloc(256 * 4);
  int* gstart = (int*)alloc((NGRAPH + 1) * 4);
  int* srcs   = (int*)alloc((size_t)E * 4);
  const int NBLK = (N + 3) / 4;
  const int nred = (NBLK + 127) / 128;
  float* partials = (float*)alloc((size_t)NBLK * 256 * 4);
  float* pr2  = (float*)alloc((size_t)nred * 256 * 4);
  float* pp   = (float*)alloc((size_t)NGRAPH * 8 * 128 * 4);
  uint4* Wpack= (uint4*)alloc((size_t)16 * 2048 * 16);
  unsigned* qh_u  = (unsigned*)alloc((size_t)N * 64 * 4);
  unsigned* kvh_u = (unsigned*)alloc((size_t)N * 128 * 4);
  float* h    = (float*)alloc((size_t)N * HD * 4);
  float* x    = (float*)alloc((size_t)N * HD * 4);
  __half* xh  = (__half*)alloc((size_t)N * HD * 2);

  hipMemsetAsync(deg, 0, (size_t)(zero_end - (char*)deg), stream);

  const int NB  = (N + 255) / 256;
  const int EB  = (E + 255) / 256;
  const int L1B = (N * 32 + 255) / 256;
  const int BFB = (N + 63) / 64;
  const float invN = 1.f / (float)N;

  // CSR build + graph bounds + weight prepack
  k_count  <<<EB, 256, 0, stream>>>(dst, deg, E);
  k_scan1  <<<NB, 256, 0, stream>>>(deg, rp, bt, N);
  k_scan2  <<<1, 256, 0, stream>>>(bt, bo, NB);
  k_scan3  <<<NB, 256, 0, stream>>>(rp, bo, N);
  k_scatter<<<EB, 256, 0, stream>>>(src, dst, rp, cursor, srcs, E);
  k_gbounds<<<1, 128, 0, stream>>>(batch, gstart, N);
  k_wpack  <<<128, 256, 0, stream>>>(Wq, Wk, Wv, Ws, Wpack);

  // layer 1
  k_layer1<<<L1B, 256, 0, stream>>>(X, Wq1,bq1, Wk1,bk1, Wv1,bv1, Ws1,bs1, qh_u, kvh_u, h, N);
  k_attn  <<<NBLK, 256, 0, stream>>>((const uint4*)qh_u, (const uint4*)kvh_u, h, partials, rp, srcs, N);
  k_red1  <<<nred, 256, 0, stream>>>(partials, pr2, NBLK);
  k_bnfin <<<BFB, 256, 0, stream>>>(h, x, xh, pr2, nred, bn_g, bn_b, N, 0, invN);

  // layers 2..5
  for (int l = 0; l < 4; ++l){
    k_gemm<<<dim3((N + 63) / 64, 4), 256, 0, stream>>>(
        xh, Wpack, bq + (size_t)l*HD, bk + (size_t)l*HD, bv + (size_t)l*HD, bs + (size_t)l*HD,
        qh_u, kvh_u, h, N, l);
    k_attn<<<NBLK, 256, 0, stream>>>((const uint4*)qh_u, (const uint4*)kvh_u, h, partials, rp, srcs, N);
    k_red1<<<nred, 256, 0, stream>>>(partials, pr2, NBLK);
    k_bnfin<<<BFB, 256, 0, stream>>>(h, x, xh, pr2, nred,
                                     bn_g + (size_t)(l+1)*HD, bn_b + (size_t)(l+1)*HD, N, 1, invN);
  }

  // pool + head
  k_pool1<<<dim3(NGRAPH, 8), 256, 0, stream>>>(x, gstart, pp, N);
  k_pool2<<<NGRAPH, 128, 0, stream>>>(pp, gstart, Wr, br, (float*)d_out);
}

// Round 6
// 1038.463 us; speedup vs baseline: 1.7839x; 1.0364x over previous
//
#include <hip/hip_runtime.h>
#include <hip/hip_fp16.h>
#include <math.h>

#define HD 128
#define NGRAPH 64

typedef _Float16 f16x8 __attribute__((ext_vector_type(8)));
typedef _Float16 f16x2 __attribute__((ext_vector_type(2)));
typedef float    f32x4 __attribute__((ext_vector_type(4)));

__device__ __forceinline__ unsigned h2bits(__half2 h){ return *(unsigned*)&h; }

__device__ __forceinline__ float fdot2u(unsigned a, unsigned b, float c){
#if __has_builtin(__builtin_amdgcn_fdot2)
  return __builtin_amdgcn_fdot2(*(f16x2*)&a, *(f16x2*)&b, c, false);
#else
  float2 fa = __half22float2(*(__half2*)&a);
  float2 fb = __half22float2(*(__half2*)&b);
  return c + fa.x*fb.x + fa.y*fb.y;
#endif
}

// ---------------- CSR build ----------------
// count + record within-dst position (single atomic pass)
__global__ __launch_bounds__(256) void k_count(const int* __restrict__ dst, int* __restrict__ deg,
                                               int* __restrict__ epos, int E){
  int e = blockIdx.x*256 + threadIdx.x;
  if (e < E) epos[e] = atomicAdd(&deg[dst[e]], 1);
}

__global__ __launch_bounds__(256) void k_scan1(const int* __restrict__ deg, int* __restrict__ rp,
                                               int* __restrict__ bt, int N){
  __shared__ int sm[256];
  int i = blockIdx.x*256 + threadIdx.x;
  int v = (i < N) ? deg[i] : 0;
  sm[threadIdx.x] = v;
  __syncthreads();
  for (int off = 1; off < 256; off <<= 1){
    int t = (threadIdx.x >= (unsigned)off) ? sm[threadIdx.x - off] : 0;
    __syncthreads();
    sm[threadIdx.x] += t;
    __syncthreads();
  }
  if (i < N) rp[i+1] = sm[threadIdx.x];
  if (threadIdx.x == 255) bt[blockIdx.x] = sm[255];
  if (blockIdx.x == 0 && threadIdx.x == 0) rp[0] = 0;
}

__global__ __launch_bounds__(256) void k_scan2(const int* __restrict__ bt, int* __restrict__ bo, int NB){
  __shared__ int sm[256];
  int t = threadIdx.x;
  int v = (t < NB) ? bt[t] : 0;
  sm[t] = v;
  __syncthreads();
  for (int off = 1; off < 256; off <<= 1){
    int u = (t >= (unsigned)off) ? sm[t - off] : 0;
    __syncthreads();
    sm[t] += u;
    __syncthreads();
  }
  if (t < NB) bo[t] = sm[t] - v;
}

__global__ __launch_bounds__(256) void k_scan3(int* __restrict__ rp, const int* __restrict__ bo, int N){
  int i = blockIdx.x*256 + threadIdx.x;
  if (i < N) rp[i+1] += bo[i >> 8];
}

// atomic-free scatter using precomputed positions
__global__ __launch_bounds__(256) void k_scatter(const int* __restrict__ src, const int* __restrict__ dst,
                                                 const int* __restrict__ rp, const int* __restrict__ epos,
                                                 int* __restrict__ srcs, int E){
  int e = blockIdx.x*256 + threadIdx.x;
  if (e < E) srcs[rp[dst[e]] + epos[e]] = src[e];
}

// ---------------- fused setup: layer1 projection + weight prepack + graph bounds ----------------
__global__ __launch_bounds__(256) void k_setup(
    const float* __restrict__ X,
    const float* __restrict__ Wq1, const float* __restrict__ bq1,
    const float* __restrict__ Wk1, const float* __restrict__ bk1,
    const float* __restrict__ Wv1, const float* __restrict__ bv1,
    const float* __restrict__ Ws1, const float* __restrict__ bs1,
    const float* __restrict__ Wq, const float* __restrict__ Wk,
    const float* __restrict__ Wv, const float* __restrict__ Ws,
    const int* __restrict__ batch, int* __restrict__ gstart,
    uint4* __restrict__ Wpack,
    unsigned* __restrict__ qh_u, unsigned* __restrict__ kvh_u, unsigned* __restrict__ h_u,
    int N, int L1B){
  int b = blockIdx.x;
  int tid = threadIdx.x;
  if (b < L1B){
    // layer 1 projection (in_dim = 1); h stored fp16 packed pairs
    int idx = b*256 + tid;
    if (idx >= N*32) return;
    int n = idx >> 5, s4 = idx & 31, c = s4 << 2;
    float xv = X[n];
    float qv[4], kk[4], vv[4], hv[4];
    #pragma unroll
    for (int i = 0; i < 4; ++i){
      qv[i] = xv*Wq1[c+i] + bq1[c+i];
      kk[i] = xv*Wk1[c+i] + bk1[c+i];
      vv[i] = xv*Wv1[c+i] + bv1[c+i];
      hv[i] = xv*Ws1[c+i] + bs1[c+i];
    }
    uint2 hw;
    hw.x = h2bits(__floats2half2_rn(hv[0], hv[1]));
    hw.y = h2bits(__floats2half2_rn(hv[2], hv[3]));
    *(uint2*)&h_u[(size_t)n*64 + (c >> 1)] = hw;
    uint2 qw;
    qw.x = h2bits(__floats2half2_rn(qv[0], qv[1]));
    qw.y = h2bits(__floats2half2_rn(qv[2], qv[3]));
    *(uint2*)&qh_u[(size_t)n*64 + (c >> 1)] = qw;
    int head = c >> 4, ch = c & 15;
    size_t kbase = (size_t)n*128 + head*16 + (ch >> 1);
    uint2 kw, vw;
    kw.x = h2bits(__floats2half2_rn(kk[0], kk[1]));
    kw.y = h2bits(__floats2half2_rn(kk[2], kk[3]));
    vw.x = h2bits(__floats2half2_rn(vv[0], vv[1]));
    vw.y = h2bits(__floats2half2_rn(vv[2], vv[3]));
    *(uint2*)&kvh_u[kbase]     = kw;
    *(uint2*)&kvh_u[kbase + 8] = vw;
  } else if (b < L1B + 128){
    // weight prepack into B-fragment order (fp16)
    int idx = (b - L1B)*256 + tid;
    int mi   = idx >> 11;
    int rem  = idx & 2047;
    int lane = rem & 63;
    int tile = rem >> 6;
    int chunk = tile >> 3, nt = tile & 7;
    int l = mi >> 2, ws = mi & 3;
    const float* W = (ws==0?Wq:ws==1?Wk:ws==2?Wv:Ws) + (size_t)l*HD*HD;
    int quad = lane >> 4;
    int n = nt*16 + (lane & 15);
    int k0 = chunk*32 + quad*8;
    __half hs[8];
    #pragma unroll
    for (int j = 0; j < 8; ++j) hs[j] = __float2half(W[(size_t)(k0+j)*HD + n]);
    Wpack[idx] = *(uint4*)hs;
  } else {
    // graph boundaries via binary search over SORTED batch
    int g = tid;
    if (g > NGRAPH) return;
    int lo = 0, hi = N;
    while (lo < hi){
      int mid = (lo + hi) >> 1;
      if (batch[mid] < g) lo = mid + 1; else hi = mid;
    }
    gstart[g] = lo;
  }
}

// ---------------- MFMA QKVS GEMM: 256 rows/block, 4 row-tiles per wave ----------------
// grid = (ceil(N/256), 4): blockIdx.y = wsel {q,k,v,h}
__global__ __launch_bounds__(256) void k_gemm(
    const __half* __restrict__ xh, const uint4* __restrict__ Wpack,
    const float* __restrict__ bq, const float* __restrict__ bk,
    const float* __restrict__ bv, const float* __restrict__ bs,
    unsigned* __restrict__ qh_u, unsigned* __restrict__ kvh_u, unsigned* __restrict__ h_u,
    int N, int layer){
  __shared__ uint4 Bs[2048];
  int wsel = blockIdx.y;
  const uint4* Wm = Wpack + (size_t)(layer*4 + wsel)*2048;
  int tid = threadIdx.x;
  for (int i = tid; i < 2048; i += 256) Bs[i] = Wm[i];

  int w = tid >> 6, lane = tid & 63;
  int l15 = lane & 15, quad = lane >> 4;
  const float* bias = (wsel==0)?bq:(wsel==1)?bk:(wsel==2)?bv:bs;

  __syncthreads();

  for (int rt = 0; rt < 4; ++rt){
    int row0 = blockIdx.x*256 + w*64 + rt*16;
    if (row0 >= N) break;
    int arow = row0 + l15;

    f32x4 acc[8];
    #pragma unroll
    for (int i = 0; i < 8; ++i) acc[i] = (f32x4){0.f,0.f,0.f,0.f};

    #pragma unroll
    for (int chunk = 0; chunk < 4; ++chunk){
      f16x8 a = {};
      if (arow < N) a = *(const f16x8*)(xh + (size_t)arow*HD + chunk*32 + quad*8);
      #pragma unroll
      for (int nt = 0; nt < 8; ++nt){
        f16x8 b = *(const f16x8*)&Bs[(chunk*8 + nt)*64 + lane];
        acc[nt] = __builtin_amdgcn_mfma_f32_16x16x32_f16(a, b, acc[nt], 0, 0, 0);
      }
    }

    // D layout: col = nt*16 + l15, row = row0 + quad*4 + reg; pack pairs via shfl
    #pragma unroll
    for (int nt = 0; nt < 8; ++nt){
      int col = nt*16 + l15;
      float b = bias[col];
      #pragma unroll
      for (int reg = 0; reg < 4; ++reg){
        float val = acc[nt][reg] + b;
        float oth = __shfl_xor(val, 1);
        int row = row0 + quad*4 + reg;
        if (!(l15 & 1) && row < N){
          unsigned pk = h2bits(__floats2half2_rn(val, oth));
          if (wsel == 0)       qh_u[(size_t)row*64  + nt*8  + (l15>>1)]      = pk;
          else if (wsel == 1)  kvh_u[(size_t)row*128 + nt*16 + (l15>>1)]     = pk;
          else if (wsel == 2)  kvh_u[(size_t)row*128 + nt*16 + (l15>>1) + 8] = pk;
          else                 h_u[(size_t)row*64  + nt*8  + (l15>>1)]       = pk;
        }
      }
    }
  }
}

// ---------------- attention: wave per node; lane = (edge-slot, head); plain-exp softmax ----------------
// h fp16 in/out; emits per-block BN partials (transposed layout, conflict-free)
__global__ __launch_bounds__(256) void k_attn(
    const uint4* __restrict__ qh4, const uint4* __restrict__ kvh4,
    unsigned* __restrict__ h_u, float* __restrict__ partials,
    const int* __restrict__ rp, const int* __restrict__ srcs, int N){
  __shared__ float ssum[4][128];
  __shared__ float ssq[4][128];
  int tid = threadIdx.x;
  int w = tid >> 6, lane = tid & 63;
  int oct = lane >> 3, hh = lane & 7;
  int n = blockIdx.x*4 + w;
  bool active = (n < N);

  float acc[16];
  #pragma unroll
  for (int i = 0; i < 16; ++i) acc[i] = 0.f;
  float lsum = 0.f;

  if (active){
    uint4 q0 = qh4[(size_t)n*16 + hh*2];
    uint4 q1 = qh4[(size_t)n*16 + hh*2 + 1];
    unsigned qr[8] = {q0.x,q0.y,q0.z,q0.w, q1.x,q1.y,q1.z,q1.w};
    int beg = rp[n], end = rp[n+1];
    for (int t = beg + oct; t < end; t += 8){
      int s = srcs[t];
      const uint4* base = kvh4 + (size_t)s*32 + hh*4;
      uint4 g0 = base[0];
      uint4 g1 = base[1];
      uint4 g2 = base[2];
      uint4 g3 = base[3];
      unsigned kr[8] = {g0.x,g0.y,g0.z,g0.w, g1.x,g1.y,g1.z,g1.w};
      float pd = 0.f;
      #pragma unroll
      for (int i = 0; i < 8; ++i) pd = fdot2u(kr[i], qr[i], pd);
      float e = __expf(pd * 0.25f);   // no max-subtract: activations BN-bounded
      lsum += e;
      unsigned vr[8] = {g2.x,g2.y,g2.z,g2.w, g3.x,g3.y,g3.z,g3.w};
      #pragma unroll
      for (int i = 0; i < 8; ++i){
        float2 vf = __half22float2(*(__half2*)&vr[i]);
        acc[2*i]   += e*vf.x;
        acc[2*i+1] += e*vf.y;
      }
    }
  }

  #pragma unroll
  for (int mask = 8; mask <= 32; mask <<= 1){
    lsum += __shfl_xor(lsum, mask);
    #pragma unroll
    for (int i = 0; i < 16; ++i) acc[i] += __shfl_xor(acc[i], mask);
  }
  float inv = (lsum > 0.f) ? 1.f/lsum : 0.f;

  float out[16];
  #pragma unroll
  for (int i = 0; i < 16; ++i) out[i] = 0.f;
  if (active && oct == 0){
    uint4* hp = (uint4*)(h_u + (size_t)n*64 + hh*8);
    uint4 s0 = hp[0], s1 = hp[1];
    unsigned sr[8] = {s0.x,s0.y,s0.z,s0.w, s1.x,s1.y,s1.z,s1.w};
    #pragma unroll
    for (int i = 0; i < 8; ++i){
      float2 sk = __half22float2(*(__half2*)&sr[i]);
      out[2*i]   = fmaxf(acc[2*i]*inv   + sk.x, 0.f);
      out[2*i+1] = fmaxf(acc[2*i+1]*inv + sk.y, 0.f);
    }
    uint4 w0, w1;
    w0.x = h2bits(__floats2half2_rn(out[0], out[1]));
    w0.y = h2bits(__floats2half2_rn(out[2], out[3]));
    w0.z = h2bits(__floats2half2_rn(out[4], out[5]));
    w0.w = h2bits(__floats2half2_rn(out[6], out[7]));
    w1.x = h2bits(__floats2half2_rn(out[8], out[9]));
    w1.y = h2bits(__floats2half2_rn(out[10], out[11]));
    w1.z = h2bits(__floats2half2_rn(out[12], out[13]));
    w1.w = h2bits(__floats2half2_rn(out[14], out[15]));
    hp[0] = w0; hp[1] = w1;
  }
  if (oct == 0){
    // transposed store: position j*8+hh <-> channel hh*16+j (8 lanes hit 8 distinct banks)
    #pragma unroll
    for (int j = 0; j < 16; ++j){
      int pidx = j*8 + hh;
      ssum[w][pidx] = out[j];
      ssq[w][pidx]  = out[j]*out[j];
    }
  }
  __syncthreads();
  if (tid < 128){
    partials[(size_t)blockIdx.x*256 + tid] = ssum[0][tid]+ssum[1][tid]+ssum[2][tid]+ssum[3][tid];
  } else {
    int c = tid - 128;
    partials[(size_t)blockIdx.x*256 + tid] = ssq[0][c]+ssq[1][c]+ssq[2][c]+ssq[3][c];
  }
}

// ---------------- BN reduce level 1 (un-permutes the transposed partial layout) ----------------
__global__ __launch_bounds__(256) void k_red1(const float* __restrict__ partials,
                                               float* __restrict__ pr2, int NBLK){
  int t = threadIdx.x, b = blockIdx.x;
  int c = t & 127;
  int p = ((c & 15) << 3) | (c >> 4);      // position holding channel c
  int off = (t < 128) ? 0 : 128;
  int r0 = b*128, r1 = min(r0 + 128, NBLK);
  float s = 0.f;
  for (int r = r0; r < r1; ++r) s += partials[(size_t)r*256 + off + p];
  pr2[(size_t)b*256 + t] = s;   // channel-ordered
}

// ---------------- BN finalize: reduce pr2 + normalize (+residual), emit x f32 and xh fp16 ----------------
__global__ __launch_bounds__(256) void k_bnfin(
    const __half* __restrict__ h, float* __restrict__ x, __half* __restrict__ xh,
    const float* __restrict__ pr2, int nred,
    const float* __restrict__ gamma, const float* __restrict__ beta,
    int N, int resid, float invN){
  int t = threadIdx.x;
  int c = t & 127;
  float s = 0.f, sq = 0.f;
  for (int i = 0; i < nred; ++i){
    s  += pr2[(size_t)i*256 + c];
    sq += pr2[(size_t)i*256 + 128 + c];
  }
  float mu  = s * invN;
  float var = sq * invN - mu*mu;
  float scl = rsqrtf(var + 1e-5f) * gamma[c];
  float bb  = beta[c] - mu*scl;
  int rend = min(blockIdx.x*64 + 64, N);
  for (int r = blockIdx.x*64 + (t >> 7); r < rend; r += 2){
    size_t idx = (size_t)r*HD + c;
    float o = __half2float(h[idx])*scl + bb;
    float xn = resid ? (x[idx] + o) : o;
    x[idx]  = xn;
    xh[idx] = __float2half(xn);
  }
}

// ---------------- pool stage 1 ----------------
__global__ __launch_bounds__(256) void k_pool1(
    const float* __restrict__ x, const int* __restrict__ gstart,
    float* __restrict__ pp, int N){
  __shared__ float sm[256];
  int g = blockIdx.x, chunk = blockIdx.y;
  int t = threadIdx.x;
  int c = t & 127, half = t >> 7;
  int start = gstart[g];
  int endr  = gstart[g+1];
  float s = 0.f;
  for (int r = start + chunk*2 + half; r < endr; r += 16) s += x[(size_t)r*HD + c];
  sm[t] = s;
  __syncthreads();
  if (t < 128) pp[(size_t)(g*8 + chunk)*128 + t] = sm[t] + sm[t + 128];
}

// ---------------- pool stage 2 ----------------
__global__ __launch_bounds__(128) void k_pool2(
    const float* __restrict__ pp, const int* __restrict__ gstart,
    const float* __restrict__ Wr, const float* __restrict__ br,
    float* __restrict__ out){
  __shared__ float sm[128];
  int g = blockIdx.x, c = threadIdx.x;
  float s = 0.f;
  #pragma unroll
  for (int j = 0; j < 8; ++j) s += pp[(size_t)(g*8 + j)*128 + c];
  int cnt = gstart[g+1] - gstart[g];
  float xm = s / fmaxf((float)cnt, 1.f);
  out[NGRAPH + g*HD + c] = xm;
  sm[c] = xm * Wr[c];
  __syncthreads();
  for (int off = 64; off > 0; off >>= 1){
    if (c < off) sm[c] += sm[c + off];
    __syncthreads();
  }
  if (c == 0) out[g] = sm[0] + br[0];
}

extern "C" void kernel_launch(void* const* d_in, const int* in_sizes, int n_in,
                              void* d_out, int out_size, void* d_ws, size_t ws_size,
                              hipStream_t stream){
  const float* X     = (const float*)d_in[0];
  const int*   ei    = (const int*)  d_in[1];
  const int*   batch = (const int*)  d_in[2];
  const float* Wq1 = (const float*)d_in[3];  const float* bq1 = (const float*)d_in[4];
  const float* Wk1 = (const float*)d_in[5];  const float* bk1 = (const float*)d_in[6];
  const float* Wv1 = (const float*)d_in[7];  const float* bv1 = (const float*)d_in[8];
  const float* Ws1 = (const float*)d_in[9];  const float* bs1 = (const float*)d_in[10];
  const float* Wq  = (const float*)d_in[11]; const float* bq  = (const float*)d_in[12];
  const float* Wk  = (const float*)d_in[13]; const float* bk  = (const float*)d_in[14];
  const float* Wv  = (const float*)d_in[15]; const float* bv  = (const float*)d_in[16];
  const float* Ws  = (const float*)d_in[17]; const float* bs  = (const float*)d_in[18];
  const float* bn_g= (const float*)d_in[19]; const float* bn_b= (const float*)d_in[20];
  const float* Wr  = (const float*)d_in[21]; const float* br  = (const float*)d_in[22];

  const int N = in_sizes[0];
  const int E = in_sizes[1] / 2;

  const int* src = ei;
  const int* dst = ei + E;

  char* p = (char*)d_ws;
  auto alloc = [&](size_t bytes) -> void* {
    void* r = (void*)p;
    p += (bytes + 255) & ~(size_t)255;
    return r;
  };
  int* deg    = (int*)alloc((size_t)N * 4);          // memset to 0
  int* rp     = (int*)alloc((size_t)(N + 1) * 4);
  int* bt     = (int*)alloc(256 * 4);
  int* bo     = (int*)alloc(256 * 4);
  int* gstart = (int*)alloc((NGRAPH + 1) * 4);
  int* epos   = (int*)alloc((size_t)E * 4);
  int* srcs   = (int*)alloc((size_t)E * 4);
  const int NBLK = (N + 3) / 4;
  const int nred = (NBLK + 127) / 128;
  float* partials = (float*)alloc((size_t)NBLK * 256 * 4);
  float* pr2  = (float*)alloc((size_t)nred * 256 * 4);
  float* pp   = (float*)alloc((size_t)NGRAPH * 8 * 128 * 4);
  uint4* Wpack= (uint4*)alloc((size_t)16 * 2048 * 16);
  unsigned* qh_u  = (unsigned*)alloc((size_t)N * 64 * 4);
  unsigned* kvh_u = (unsigned*)alloc((size_t)N * 128 * 4);
  unsigned* h_u   = (unsigned*)alloc((size_t)N * 64 * 4);   // h as fp16 pairs
  float* x    = (float*)alloc((size_t)N * HD * 4);
  __half* xh  = (__half*)alloc((size_t)N * HD * 2);

  hipMemsetAsync(deg, 0, (size_t)N * 4, stream);

  const int NB  = (N + 255) / 256;
  const int EB  = (E + 255) / 256;
  const int L1B = (N * 32 + 255) / 256;
  const int BFB = (N + 63) / 64;
  const float invN = 1.f / (float)N;

  // CSR build (single atomic pass) + fused setup
  k_count  <<<EB, 256, 0, stream>>>(dst, deg, epos, E);
  k_scan1  <<<NB, 256, 0, stream>>>(deg, rp, bt, N);
  k_scan2  <<<1, 256, 0, stream>>>(bt, bo, NB);
  k_scan3  <<<NB, 256, 0, stream>>>(rp, bo, N);
  k_scatter<<<EB, 256, 0, stream>>>(src, dst, rp, epos, srcs, E);
  k_setup  <<<L1B + 129, 256, 0, stream>>>(X, Wq1,bq1, Wk1,bk1, Wv1,bv1, Ws1,bs1,
                                           Wq, Wk, Wv, Ws, batch, gstart, Wpack,
                                           qh_u, kvh_u, h_u, N, L1B);

  // layer 1
  k_attn <<<NBLK, 256, 0, stream>>>((const uint4*)qh_u, (const uint4*)kvh_u, h_u, partials, rp, srcs, N);
  k_red1 <<<nred, 256, 0, stream>>>(partials, pr2, NBLK);
  k_bnfin<<<BFB, 256, 0, stream>>>((const __half*)h_u, x, xh, pr2, nred, bn_g, bn_b, N, 0, invN);

  // layers 2..5
  for (int l = 0; l < 4; ++l){
    k_gemm<<<dim3((N + 255) / 256, 4), 256, 0, stream>>>(
        xh, Wpack, bq + (size_t)l*HD, bk + (size_t)l*HD, bv + (size_t)l*HD, bs + (size_t)l*HD,
        qh_u, kvh_u, h_u, N, l);
    k_attn<<<NBLK, 256, 0, stream>>>((const uint4*)qh_u, (const uint4*)kvh_u, h_u, partials, rp, srcs, N);
    k_red1<<<nred, 256, 0, stream>>>(partials, pr2, NBLK);
    k_bnfin<<<BFB, 256, 0, stream>>>((const __half*)h_u, x, xh, pr2, nred,
                                     bn_g + (size_t)(l+1)*HD, bn_b + (size_t)(l+1)*HD, N, 1, invN);
  }

  // pool + head
  k_pool1<<<dim3(NGRAPH, 8), 256, 0, stream>>>(x, gstart, pp, N);
  k_pool2<<<NGRAPH, 128, 0, stream>>>(pp, gstart, Wr, br, (float*)d_out);
}

// Round 7
// 984.683 us; speedup vs baseline: 1.8813x; 1.0546x over previous
//
#include <hip/hip_runtime.h>
#include <hip/hip_fp16.h>
#include <math.h>

#define HD 128
#define NGRAPH 64

typedef _Float16 f16x8 __attribute__((ext_vector_type(8)));
typedef _Float16 f16x2 __attribute__((ext_vector_type(2)));
typedef float    f32x4 __attribute__((ext_vector_type(4)));

__device__ __forceinline__ unsigned h2bits(__half2 h){ return *(unsigned*)&h; }

__device__ __forceinline__ float fdot2u(unsigned a, unsigned b, float c){
#if __has_builtin(__builtin_amdgcn_fdot2)
  return __builtin_amdgcn_fdot2(*(f16x2*)&a, *(f16x2*)&b, c, false);
#else
  float2 fa = __half22float2(*(__half2*)&a);
  float2 fb = __half22float2(*(__half2*)&b);
  return c + fa.x*fb.x + fa.y*fb.y;
#endif
}

// ---------------- fused: CSR count (atomic pos) + layer1 projection + wpack + gbounds ----------------
__global__ __launch_bounds__(256) void k_count_setup(
    const int* __restrict__ dst, int* __restrict__ deg, int* __restrict__ epos, int E, int EB,
    const float* __restrict__ X,
    const float* __restrict__ Wq1, const float* __restrict__ bq1,
    const float* __restrict__ Wk1, const float* __restrict__ bk1,
    const float* __restrict__ Wv1, const float* __restrict__ bv1,
    const float* __restrict__ Ws1, const float* __restrict__ bs1,
    const float* __restrict__ Wq, const float* __restrict__ Wk,
    const float* __restrict__ Wv, const float* __restrict__ Ws,
    const int* __restrict__ batch, int* __restrict__ gstart,
    uint4* __restrict__ Wpack,
    unsigned* __restrict__ qh_u, unsigned* __restrict__ kvh_u, unsigned* __restrict__ h_u,
    int N, int L1B){
  int b = blockIdx.x;
  int tid = threadIdx.x;
  if (b < EB){
    int e = b*256 + tid;
    if (e < E) epos[e] = atomicAdd(&deg[dst[e]], 1);
  } else if (b < EB + L1B){
    int idx = (b - EB)*256 + tid;
    if (idx >= N*32) return;
    int n = idx >> 5, s4 = idx & 31, c = s4 << 2;
    float xv = X[n];
    float qv[4], kk[4], vv[4], hv[4];
    #pragma unroll
    for (int i = 0; i < 4; ++i){
      qv[i] = xv*Wq1[c+i] + bq1[c+i];
      kk[i] = xv*Wk1[c+i] + bk1[c+i];
      vv[i] = xv*Wv1[c+i] + bv1[c+i];
      hv[i] = xv*Ws1[c+i] + bs1[c+i];
    }
    uint2 hw;
    hw.x = h2bits(__floats2half2_rn(hv[0], hv[1]));
    hw.y = h2bits(__floats2half2_rn(hv[2], hv[3]));
    *(uint2*)&h_u[(size_t)n*64 + (c >> 1)] = hw;
    uint2 qw;
    qw.x = h2bits(__floats2half2_rn(qv[0], qv[1]));
    qw.y = h2bits(__floats2half2_rn(qv[2], qv[3]));
    *(uint2*)&qh_u[(size_t)n*64 + (c >> 1)] = qw;
    int head = c >> 4, ch = c & 15;
    size_t kbase = (size_t)n*128 + head*16 + (ch >> 1);
    uint2 kw, vw;
    kw.x = h2bits(__floats2half2_rn(kk[0], kk[1]));
    kw.y = h2bits(__floats2half2_rn(kk[2], kk[3]));
    vw.x = h2bits(__floats2half2_rn(vv[0], vv[1]));
    vw.y = h2bits(__floats2half2_rn(vv[2], vv[3]));
    *(uint2*)&kvh_u[kbase]     = kw;
    *(uint2*)&kvh_u[kbase + 8] = vw;
  } else if (b < EB + L1B + 128){
    int idx = (b - EB - L1B)*256 + tid;
    int mi   = idx >> 11;
    int rem  = idx & 2047;
    int lane = rem & 63;
    int tile = rem >> 6;
    int chunk = tile >> 3, nt = tile & 7;
    int l = mi >> 2, ws = mi & 3;
    const float* W = (ws==0?Wq:ws==1?Wk:ws==2?Wv:Ws) + (size_t)l*HD*HD;
    int quad = lane >> 4;
    int n = nt*16 + (lane & 15);
    int k0 = chunk*32 + quad*8;
    __half hs[8];
    #pragma unroll
    for (int j = 0; j < 8; ++j) hs[j] = __float2half(W[(size_t)(k0+j)*HD + n]);
    Wpack[idx] = *(uint4*)hs;
  } else {
    int g = tid;
    if (g > NGRAPH) return;
    int lo = 0, hi = N;
    while (lo < hi){
      int mid = (lo + hi) >> 1;
      if (batch[mid] < g) lo = mid + 1; else hi = mid;
    }
    gstart[g] = lo;
  }
}

// ---------------- scan stage 1: per-block inclusive scan + block totals ----------------
__global__ __launch_bounds__(256) void k_scan1(const int* __restrict__ deg, int* __restrict__ rp,
                                               int* __restrict__ bt, int N){
  __shared__ int sm[256];
  int i = blockIdx.x*256 + threadIdx.x;
  int v = (i < N) ? deg[i] : 0;
  sm[threadIdx.x] = v;
  __syncthreads();
  for (int off = 1; off < 256; off <<= 1){
    int t = (threadIdx.x >= (unsigned)off) ? sm[threadIdx.x - off] : 0;
    __syncthreads();
    sm[threadIdx.x] += t;
    __syncthreads();
  }
  if (i < N) rp[i+1] = sm[threadIdx.x];
  if (threadIdx.x == 255) bt[blockIdx.x] = sm[255];
  if (blockIdx.x == 0 && threadIdx.x == 0) rp[0] = 0;
}

// ---------------- scan stage 2 (fused): each block reduces bt[0..b) and adds ----------------
// requires NB <= 256
__global__ __launch_bounds__(256) void k_scan3(int* __restrict__ rp, const int* __restrict__ bt, int N){
  __shared__ int sm[256];
  int b = blockIdx.x, t = threadIdx.x;
  sm[t] = (t < b) ? bt[t] : 0;
  __syncthreads();
  for (int off = 128; off > 0; off >>= 1){
    if (t < off) sm[t] += sm[t + off];
    __syncthreads();
  }
  int offset = sm[0];
  int i = b*256 + t;
  if (i < N) rp[i+1] += offset;
}

// atomic-free scatter using precomputed positions
__global__ __launch_bounds__(256) void k_scatter(const int* __restrict__ src, const int* __restrict__ dst,
                                                 const int* __restrict__ rp, const int* __restrict__ epos,
                                                 int* __restrict__ srcs, int E){
  int e = blockIdx.x*256 + threadIdx.x;
  if (e < E) srcs[rp[dst[e]] + epos[e]] = src[e];
}

// ---------------- MFMA QKVS GEMM: 256 rows/block, 4 row-tiles per wave ----------------
// grid = (ceil(N/256), 4): blockIdx.y = wsel {q,k,v,h}; x is fp16
__global__ __launch_bounds__(256) void k_gemm(
    const __half* __restrict__ x, const uint4* __restrict__ Wpack,
    const float* __restrict__ bq, const float* __restrict__ bk,
    const float* __restrict__ bv, const float* __restrict__ bs,
    unsigned* __restrict__ qh_u, unsigned* __restrict__ kvh_u, unsigned* __restrict__ h_u,
    int N, int layer){
  __shared__ uint4 Bs[2048];
  int wsel = blockIdx.y;
  const uint4* Wm = Wpack + (size_t)(layer*4 + wsel)*2048;
  int tid = threadIdx.x;
  for (int i = tid; i < 2048; i += 256) Bs[i] = Wm[i];

  int w = tid >> 6, lane = tid & 63;
  int l15 = lane & 15, quad = lane >> 4;
  const float* bias = (wsel==0)?bq:(wsel==1)?bk:(wsel==2)?bv:bs;

  __syncthreads();

  for (int rt = 0; rt < 4; ++rt){
    int row0 = blockIdx.x*256 + w*64 + rt*16;
    if (row0 >= N) break;
    int arow = row0 + l15;

    f32x4 acc[8];
    #pragma unroll
    for (int i = 0; i < 8; ++i) acc[i] = (f32x4){0.f,0.f,0.f,0.f};

    #pragma unroll
    for (int chunk = 0; chunk < 4; ++chunk){
      f16x8 a = {};
      if (arow < N) a = *(const f16x8*)(x + (size_t)arow*HD + chunk*32 + quad*8);
      #pragma unroll
      for (int nt = 0; nt < 8; ++nt){
        f16x8 b = *(const f16x8*)&Bs[(chunk*8 + nt)*64 + lane];
        acc[nt] = __builtin_amdgcn_mfma_f32_16x16x32_f16(a, b, acc[nt], 0, 0, 0);
      }
    }

    #pragma unroll
    for (int nt = 0; nt < 8; ++nt){
      int col = nt*16 + l15;
      float b = bias[col];
      #pragma unroll
      for (int reg = 0; reg < 4; ++reg){
        float val = acc[nt][reg] + b;
        float oth = __shfl_xor(val, 1);
        int row = row0 + quad*4 + reg;
        if (!(l15 & 1) && row < N){
          unsigned pk = h2bits(__floats2half2_rn(val, oth));
          if (wsel == 0)       qh_u[(size_t)row*64  + nt*8  + (l15>>1)]      = pk;
          else if (wsel == 1)  kvh_u[(size_t)row*128 + nt*16 + (l15>>1)]     = pk;
          else if (wsel == 2)  kvh_u[(size_t)row*128 + nt*16 + (l15>>1) + 8] = pk;
          else                 h_u[(size_t)row*64  + nt*8  + (l15>>1)]       = pk;
        }
      }
    }
  }
}

// ---------------- attention: wave per node; register double-buffered edge loop ----------------
// BN partials: block-LDS merge then atomicAdd into pr2 row (blockIdx & 63), layer-parity buffer
__global__ __launch_bounds__(256) void k_attn(
    const uint4* __restrict__ qh4, const uint4* __restrict__ kvh4,
    unsigned* __restrict__ h_u, float* __restrict__ pr2,
    const int* __restrict__ rp, const int* __restrict__ srcs, int N, int layer){
  __shared__ float ssum[4][128];
  __shared__ float ssq[4][128];
  int tid = threadIdx.x;
  int w = tid >> 6, lane = tid & 63;
  int oct = lane >> 3, hh = lane & 7;
  int n = blockIdx.x*4 + w;
  bool active = (n < N);

  float acc[16];
  #pragma unroll
  for (int i = 0; i < 16; ++i) acc[i] = 0.f;
  float lsum = 0.f;

  if (active){
    uint4 q0 = qh4[(size_t)n*16 + hh*2];
    uint4 q1 = qh4[(size_t)n*16 + hh*2 + 1];
    unsigned qr[8] = {q0.x,q0.y,q0.z,q0.w, q1.x,q1.y,q1.z,q1.w};
    int beg = rp[n], end = rp[n+1];
    int t = beg + oct;
    bool vcur = (t < end);
    uint4 g0, g1, g2, g3;
    if (vcur){
      const uint4* base = kvh4 + (size_t)srcs[t]*32 + hh*4;
      g0 = base[0]; g1 = base[1]; g2 = base[2]; g3 = base[3];
    }
    while (vcur){
      int tn = t + 8;
      bool vn = (tn < end);
      int sn = vn ? srcs[tn] : 0;
      const uint4* nb = kvh4 + (size_t)sn*32 + hh*4;
      uint4 n0 = nb[0], n1 = nb[1], n2 = nb[2], n3 = nb[3];   // prefetch next (node 0 when tail)

      unsigned kr[8] = {g0.x,g0.y,g0.z,g0.w, g1.x,g1.y,g1.z,g1.w};
      float pd = 0.f;
      #pragma unroll
      for (int i = 0; i < 8; ++i) pd = fdot2u(kr[i], qr[i], pd);
      float e = __expf(pd * 0.25f);   // no max-subtract: activations BN-bounded
      lsum += e;
      unsigned vr[8] = {g2.x,g2.y,g2.z,g2.w, g3.x,g3.y,g3.z,g3.w};
      #pragma unroll
      for (int i = 0; i < 8; ++i){
        float2 vf = __half22float2(*(__half2*)&vr[i]);
        acc[2*i]   += e*vf.x;
        acc[2*i+1] += e*vf.y;
      }
      g0 = n0; g1 = n1; g2 = n2; g3 = n3;
      t = tn; vcur = vn;
    }
  }

  #pragma unroll
  for (int mask = 8; mask <= 32; mask <<= 1){
    lsum += __shfl_xor(lsum, mask);
    #pragma unroll
    for (int i = 0; i < 16; ++i) acc[i] += __shfl_xor(acc[i], mask);
  }
  float inv = (lsum > 0.f) ? 1.f/lsum : 0.f;

  float out[16];
  #pragma unroll
  for (int i = 0; i < 16; ++i) out[i] = 0.f;
  if (active && oct == 0){
    uint4* hp = (uint4*)(h_u + (size_t)n*64 + hh*8);
    uint4 s0 = hp[0], s1 = hp[1];
    unsigned sr[8] = {s0.x,s0.y,s0.z,s0.w, s1.x,s1.y,s1.z,s1.w};
    #pragma unroll
    for (int i = 0; i < 8; ++i){
      float2 sk = __half22float2(*(__half2*)&sr[i]);
      out[2*i]   = fmaxf(acc[2*i]*inv   + sk.x, 0.f);
      out[2*i+1] = fmaxf(acc[2*i+1]*inv + sk.y, 0.f);
    }
    uint4 w0, w1;
    w0.x = h2bits(__floats2half2_rn(out[0], out[1]));
    w0.y = h2bits(__floats2half2_rn(out[2], out[3]));
    w0.z = h2bits(__floats2half2_rn(out[4], out[5]));
    w0.w = h2bits(__floats2half2_rn(out[6], out[7]));
    w1.x = h2bits(__floats2half2_rn(out[8], out[9]));
    w1.y = h2bits(__floats2half2_rn(out[10], out[11]));
    w1.z = h2bits(__floats2half2_rn(out[12], out[13]));
    w1.w = h2bits(__floats2half2_rn(out[14], out[15]));
    hp[0] = w0; hp[1] = w1;
  }
  if (oct == 0){
    // transposed, conflict-free: position j*8+hh holds channel hh*16+j
    #pragma unroll
    for (int j = 0; j < 16; ++j){
      int pidx = j*8 + hh;
      ssum[w][pidx] = out[j];
      ssq[w][pidx]  = out[j]*out[j];
    }
  }
  __syncthreads();
  float* prow = pr2 + (size_t)(layer & 1)*16384 + (size_t)(blockIdx.x & 63)*256;
  if (tid < 128){
    atomicAdd(&prow[tid], ssum[0][tid]+ssum[1][tid]+ssum[2][tid]+ssum[3][tid]);
  } else {
    int c = tid - 128;
    atomicAdd(&prow[tid], ssq[0][c]+ssq[1][c]+ssq[2][c]+ssq[3][c]);
  }
}

// ---------------- BN finalize: reduce 64-row pr2 + normalize (+residual), x fp16; zero other pr2 buf ----------------
__global__ __launch_bounds__(256) void k_bnfin(
    const __half* __restrict__ h, __half* __restrict__ x,
    float* __restrict__ pr2, int layer,
    const float* __restrict__ gamma, const float* __restrict__ beta,
    int N, int resid, float invN){
  int t = threadIdx.x;
  int c = t & 127;
  int p = ((c & 15) << 3) | (c >> 4);   // position holding channel c
  const float* pb = pr2 + (size_t)(layer & 1)*16384;
  float s = 0.f, sq = 0.f;
  #pragma unroll 4
  for (int i = 0; i < 64; ++i){
    s  += pb[i*256 + p];
    sq += pb[i*256 + 128 + p];
  }
  float mu  = s * invN;
  float var = sq * invN - mu*mu;
  float scl = rsqrtf(var + 1e-5f) * gamma[c];
  float bb  = beta[c] - mu*scl;
  int rend = min(blockIdx.x*64 + 64, N);
  for (int r = blockIdx.x*64 + (t >> 7); r < rend; r += 2){
    size_t idx = (size_t)r*HD + c;
    float o = __half2float(h[idx])*scl + bb;
    float xn = resid ? (__half2float(x[idx]) + o) : o;
    x[idx] = __float2half(xn);
  }
  // zero the buffer the NEXT attn layer will accumulate into
  if (blockIdx.x < 64){
    pr2[(size_t)((layer + 1) & 1)*16384 + (size_t)blockIdx.x*256 + t] = 0.f;
  }
}

// ---------------- pool stage 1 (x fp16) ----------------
__global__ __launch_bounds__(256) void k_pool1(
    const __half* __restrict__ x, const int* __restrict__ gstart,
    float* __restrict__ pp, int N){
  __shared__ float sm[256];
  int g = blockIdx.x, chunk = blockIdx.y;
  int t = threadIdx.x;
  int c = t & 127, half = t >> 7;
  int start = gstart[g];
  int endr  = gstart[g+1];
  float s = 0.f;
  for (int r = start + chunk*2 + half; r < endr; r += 16) s += __half2float(x[(size_t)r*HD + c]);
  sm[t] = s;
  __syncthreads();
  if (t < 128) pp[(size_t)(g*8 + chunk)*128 + t] = sm[t] + sm[t + 128];
}

// ---------------- pool stage 2 ----------------
__global__ __launch_bounds__(128) void k_pool2(
    const float* __restrict__ pp, const int* __restrict__ gstart,
    const float* __restrict__ Wr, const float* __restrict__ br,
    float* __restrict__ out){
  __shared__ float sm[128];
  int g = blockIdx.x, c = threadIdx.x;
  float s = 0.f;
  #pragma unroll
  for (int j = 0; j < 8; ++j) s += pp[(size_t)(g*8 + j)*128 + c];
  int cnt = gstart[g+1] - gstart[g];
  float xm = s / fmaxf((float)cnt, 1.f);
  out[NGRAPH + g*HD + c] = xm;
  sm[c] = xm * Wr[c];
  __syncthreads();
  for (int off = 64; off > 0; off >>= 1){
    if (c < off) sm[c] += sm[c + off];
    __syncthreads();
  }
  if (c == 0) out[g] = sm[0] + br[0];
}

extern "C" void kernel_launch(void* const* d_in, const int* in_sizes, int n_in,
                              void* d_out, int out_size, void* d_ws, size_t ws_size,
                              hipStream_t stream){
  const float* X     = (const float*)d_in[0];
  const int*   ei    = (const int*)  d_in[1];
  const int*   batch = (const int*)  d_in[2];
  const float* Wq1 = (const float*)d_in[3];  const float* bq1 = (const float*)d_in[4];
  const float* Wk1 = (const float*)d_in[5];  const float* bk1 = (const float*)d_in[6];
  const float* Wv1 = (const float*)d_in[7];  const float* bv1 = (const float*)d_in[8];
  const float* Ws1 = (const float*)d_in[9];  const float* bs1 = (const float*)d_in[10];
  const float* Wq  = (const float*)d_in[11]; const float* bq  = (const float*)d_in[12];
  const float* Wk  = (const float*)d_in[13]; const float* bk  = (const float*)d_in[14];
  const float* Wv  = (const float*)d_in[15]; const float* bv  = (const float*)d_in[16];
  const float* Ws  = (const float*)d_in[17]; const float* bs  = (const float*)d_in[18];
  const float* bn_g= (const float*)d_in[19]; const float* bn_b= (const float*)d_in[20];
  const float* Wr  = (const float*)d_in[21]; const float* br  = (const float*)d_in[22];

  const int N = in_sizes[0];
  const int E = in_sizes[1] / 2;

  const int* src = ei;
  const int* dst = ei + E;

  char* p = (char*)d_ws;
  auto alloc = [&](size_t bytes) -> void* {
    void* r = (void*)p;
    p += (bytes + 255) & ~(size_t)255;
    return r;
  };
  int*   deg  = (int*)alloc((size_t)N * 4);           // zeroed
  float* pr2  = (float*)alloc(2 * 64 * 256 * 4);      // zeroed (both parity buffers)
  char* zero_end = p;
  int* rp     = (int*)alloc((size_t)(N + 1) * 4);
  int* bt     = (int*)alloc(256 * 4);
  int* gstart = (int*)alloc((NGRAPH + 1) * 4);
  int* epos   = (int*)alloc((size_t)E * 4);
  int* srcs   = (int*)alloc((size_t)E * 4);
  float* pp   = (float*)alloc((size_t)NGRAPH * 8 * 128 * 4);
  uint4* Wpack= (uint4*)alloc((size_t)16 * 2048 * 16);
  unsigned* qh_u  = (unsigned*)alloc((size_t)N * 64 * 4);
  unsigned* kvh_u = (unsigned*)alloc((size_t)N * 128 * 4);
  unsigned* h_u   = (unsigned*)alloc((size_t)N * 64 * 4);
  __half* x   = (__half*)alloc((size_t)N * HD * 2);

  hipMemsetAsync(deg, 0, (size_t)(zero_end - (char*)deg), stream);

  const int NB  = (N + 255) / 256;
  const int EB  = (E + 255) / 256;
  const int L1B = (N * 32 + 255) / 256;
  const int BFB = (N + 63) / 64;
  const int NBLK = (N + 3) / 4;
  const float invN = 1.f / (float)N;

  // fused count+setup, then scans + scatter
  k_count_setup<<<EB + L1B + 129, 256, 0, stream>>>(
      dst, deg, epos, E, EB,
      X, Wq1,bq1, Wk1,bk1, Wv1,bv1, Ws1,bs1,
      Wq, Wk, Wv, Ws, batch, gstart, Wpack, qh_u, kvh_u, h_u, N, L1B);
  k_scan1  <<<NB, 256, 0, stream>>>(deg, rp, bt, N);
  k_scan3  <<<NB, 256, 0, stream>>>(rp, bt, N);
  k_scatter<<<EB, 256, 0, stream>>>(src, dst, rp, epos, srcs, E);

  // layer 1 (layer index 0)
  k_attn <<<NBLK, 256, 0, stream>>>((const uint4*)qh_u, (const uint4*)kvh_u, h_u, pr2, rp, srcs, N, 0);
  k_bnfin<<<BFB, 256, 0, stream>>>((const __half*)h_u, x, pr2, 0, bn_g, bn_b, N, 0, invN);

  // layers 2..5 (layer index 1..4)
  for (int l = 0; l < 4; ++l){
    k_gemm<<<dim3((N + 255) / 256, 4), 256, 0, stream>>>(
        x, Wpack, bq + (size_t)l*HD, bk + (size_t)l*HD, bv + (size_t)l*HD, bs + (size_t)l*HD,
        qh_u, kvh_u, h_u, N, l);
    k_attn<<<NBLK, 256, 0, stream>>>((const uint4*)qh_u, (const uint4*)kvh_u, h_u, pr2, rp, srcs, N, l + 1);
    k_bnfin<<<BFB, 256, 0, stream>>>((const __half*)h_u, x, pr2, l + 1,
                                     bn_g + (size_t)(l+1)*HD, bn_b + (size_t)(l+1)*HD, N, 1, invN);
  }

  // pool + head
  k_pool1<<<dim3(NGRAPH, 8), 256, 0, stream>>>(x, gstart, pp, N);
  k_pool2<<<NGRAPH, 128, 0, stream>>>(pp, gstart, Wr, br, (float*)d_out);
}

// Round 8
// 709.956 us; speedup vs baseline: 2.6093x; 1.3870x over previous
//
#include <hip/hip_runtime.h>
#include <hip/hip_fp16.h>
#include <math.h>

#define HD 128
#define NGRAPH 64

typedef _Float16 f16x8 __attribute__((ext_vector_type(8)));
typedef _Float16 f16x2 __attribute__((ext_vector_type(2)));
typedef float    f32x4 __attribute__((ext_vector_type(4)));

__device__ __forceinline__ unsigned h2bits(__half2 h){ return *(unsigned*)&h; }

__device__ __forceinline__ float fdot2u(unsigned a, unsigned b, float c){
#if __has_builtin(__builtin_amdgcn_fdot2)
  return __builtin_amdgcn_fdot2(*(f16x2*)&a, *(f16x2*)&b, c, false);
#else
  float2 fa = __half22float2(*(__half2*)&a);
  float2 fb = __half22float2(*(__half2*)&b);
  return c + fa.x*fb.x + fa.y*fb.y;
#endif
}

// ---------------- fused: CSR count (atomic pos) + layer1 projection + wpack + gbounds ----------------
__global__ __launch_bounds__(256) void k_count_setup(
    const int* __restrict__ dst, int* __restrict__ deg, int* __restrict__ epos, int E, int EB,
    const float* __restrict__ X,
    const float* __restrict__ Wq1, const float* __restrict__ bq1,
    const float* __restrict__ Wk1, const float* __restrict__ bk1,
    const float* __restrict__ Wv1, const float* __restrict__ bv1,
    const float* __restrict__ Ws1, const float* __restrict__ bs1,
    const float* __restrict__ Wq, const float* __restrict__ Wk,
    const float* __restrict__ Wv, const float* __restrict__ Ws,
    const int* __restrict__ batch, int* __restrict__ gstart,
    uint4* __restrict__ Wpack,
    unsigned* __restrict__ qh_u, unsigned* __restrict__ kvh_u, unsigned* __restrict__ h_u,
    int N, int L1B){
  int b = blockIdx.x;
  int tid = threadIdx.x;
  if (b < EB){
    int e = b*256 + tid;
    if (e < E) epos[e] = atomicAdd(&deg[dst[e]], 1);
  } else if (b < EB + L1B){
    int idx = (b - EB)*256 + tid;
    if (idx >= N*32) return;
    int n = idx >> 5, s4 = idx & 31, c = s4 << 2;
    float xv = X[n];
    float qv[4], kk[4], vv[4], hv[4];
    #pragma unroll
    for (int i = 0; i < 4; ++i){
      qv[i] = xv*Wq1[c+i] + bq1[c+i];
      kk[i] = xv*Wk1[c+i] + bk1[c+i];
      vv[i] = xv*Wv1[c+i] + bv1[c+i];
      hv[i] = xv*Ws1[c+i] + bs1[c+i];
    }
    uint2 hw;
    hw.x = h2bits(__floats2half2_rn(hv[0], hv[1]));
    hw.y = h2bits(__floats2half2_rn(hv[2], hv[3]));
    *(uint2*)&h_u[(size_t)n*64 + (c >> 1)] = hw;
    uint2 qw;
    qw.x = h2bits(__floats2half2_rn(qv[0], qv[1]));
    qw.y = h2bits(__floats2half2_rn(qv[2], qv[3]));
    *(uint2*)&qh_u[(size_t)n*64 + (c >> 1)] = qw;
    int head = c >> 4, ch = c & 15;
    size_t kbase = (size_t)n*128 + head*16 + (ch >> 1);
    uint2 kw, vw;
    kw.x = h2bits(__floats2half2_rn(kk[0], kk[1]));
    kw.y = h2bits(__floats2half2_rn(kk[2], kk[3]));
    vw.x = h2bits(__floats2half2_rn(vv[0], vv[1]));
    vw.y = h2bits(__floats2half2_rn(vv[2], vv[3]));
    *(uint2*)&kvh_u[kbase]     = kw;
    *(uint2*)&kvh_u[kbase + 8] = vw;
  } else if (b < EB + L1B + 128){
    int idx = (b - EB - L1B)*256 + tid;
    int mi   = idx >> 11;
    int rem  = idx & 2047;
    int lane = rem & 63;
    int tile = rem >> 6;
    int chunk = tile >> 3, nt = tile & 7;
    int l = mi >> 2, ws = mi & 3;
    const float* W = (ws==0?Wq:ws==1?Wk:ws==2?Wv:Ws) + (size_t)l*HD*HD;
    int quad = lane >> 4;
    int n = nt*16 + (lane & 15);
    int k0 = chunk*32 + quad*8;
    __half hs[8];
    #pragma unroll
    for (int j = 0; j < 8; ++j) hs[j] = __float2half(W[(size_t)(k0+j)*HD + n]);
    Wpack[idx] = *(uint4*)hs;
  } else {
    int g = tid;
    if (g > NGRAPH) return;
    int lo = 0, hi = N;
    while (lo < hi){
      int mid = (lo + hi) >> 1;
      if (batch[mid] < g) lo = mid + 1; else hi = mid;
    }
    gstart[g] = lo;
  }
}

// ---------------- scan stage 1 ----------------
__global__ __launch_bounds__(256) void k_scan1(const int* __restrict__ deg, int* __restrict__ rp,
                                               int* __restrict__ bt, int N){
  __shared__ int sm[256];
  int i = blockIdx.x*256 + threadIdx.x;
  int v = (i < N) ? deg[i] : 0;
  sm[threadIdx.x] = v;
  __syncthreads();
  for (int off = 1; off < 256; off <<= 1){
    int t = (threadIdx.x >= (unsigned)off) ? sm[threadIdx.x - off] : 0;
    __syncthreads();
    sm[threadIdx.x] += t;
    __syncthreads();
  }
  if (i < N) rp[i+1] = sm[threadIdx.x];
  if (threadIdx.x == 255) bt[blockIdx.x] = sm[255];
  if (blockIdx.x == 0 && threadIdx.x == 0) rp[0] = 0;
}

// ---------------- scan stage 2 (fused; NB <= 256) ----------------
__global__ __launch_bounds__(256) void k_scan3(int* __restrict__ rp, const int* __restrict__ bt, int N){
  __shared__ int sm[256];
  int b = blockIdx.x, t = threadIdx.x;
  sm[t] = (t < b) ? bt[t] : 0;
  __syncthreads();
  for (int off = 128; off > 0; off >>= 1){
    if (t < off) sm[t] += sm[t + off];
    __syncthreads();
  }
  int offset = sm[0];
  int i = b*256 + t;
  if (i < N) rp[i+1] += offset;
}

__global__ __launch_bounds__(256) void k_scatter(const int* __restrict__ src, const int* __restrict__ dst,
                                                 const int* __restrict__ rp, const int* __restrict__ epos,
                                                 int* __restrict__ srcs, int E){
  int e = blockIdx.x*256 + threadIdx.x;
  if (e < E) srcs[rp[dst[e]] + epos[e]] = src[e];
}

// ---------------- MFMA QKVS GEMM ----------------
__global__ __launch_bounds__(256) void k_gemm(
    const __half* __restrict__ x, const uint4* __restrict__ Wpack,
    const float* __restrict__ bq, const float* __restrict__ bk,
    const float* __restrict__ bv, const float* __restrict__ bs,
    unsigned* __restrict__ qh_u, unsigned* __restrict__ kvh_u, unsigned* __restrict__ h_u,
    int N, int layer){
  __shared__ uint4 Bs[2048];
  int wsel = blockIdx.y;
  const uint4* Wm = Wpack + (size_t)(layer*4 + wsel)*2048;
  int tid = threadIdx.x;
  for (int i = tid; i < 2048; i += 256) Bs[i] = Wm[i];

  int w = tid >> 6, lane = tid & 63;
  int l15 = lane & 15, quad = lane >> 4;
  const float* bias = (wsel==0)?bq:(wsel==1)?bk:(wsel==2)?bv:bs;

  __syncthreads();

  for (int rt = 0; rt < 4; ++rt){
    int row0 = blockIdx.x*256 + w*64 + rt*16;
    if (row0 >= N) break;
    int arow = row0 + l15;

    f32x4 acc[8];
    #pragma unroll
    for (int i = 0; i < 8; ++i) acc[i] = (f32x4){0.f,0.f,0.f,0.f};

    #pragma unroll
    for (int chunk = 0; chunk < 4; ++chunk){
      f16x8 a = {};
      if (arow < N) a = *(const f16x8*)(x + (size_t)arow*HD + chunk*32 + quad*8);
      #pragma unroll
      for (int nt = 0; nt < 8; ++nt){
        f16x8 b = *(const f16x8*)&Bs[(chunk*8 + nt)*64 + lane];
        acc[nt] = __builtin_amdgcn_mfma_f32_16x16x32_f16(a, b, acc[nt], 0, 0, 0);
      }
    }

    #pragma unroll
    for (int nt = 0; nt < 8; ++nt){
      int col = nt*16 + l15;
      float b = bias[col];
      #pragma unroll
      for (int reg = 0; reg < 4; ++reg){
        float val = acc[nt][reg] + b;
        float oth = __shfl_xor(val, 1);
        int row = row0 + quad*4 + reg;
        if (!(l15 & 1) && row < N){
          unsigned pk = h2bits(__floats2half2_rn(val, oth));
          if (wsel == 0)       qh_u[(size_t)row*64  + nt*8  + (l15>>1)]      = pk;
          else if (wsel == 1)  kvh_u[(size_t)row*128 + nt*16 + (l15>>1)]     = pk;
          else if (wsel == 2)  kvh_u[(size_t)row*128 + nt*16 + (l15>>1) + 8] = pk;
          else                 h_u[(size_t)row*64  + nt*8  + (l15>>1)]       = pk;
        }
      }
    }
  }
}

// ---------------- attention ----------------
__global__ __launch_bounds__(256) void k_attn(
    const uint4* __restrict__ qh4, const uint4* __restrict__ kvh4,
    unsigned* __restrict__ h_u, float* __restrict__ pr2,
    const int* __restrict__ rp, const int* __restrict__ srcs, int N, int layer){
  __shared__ float ssum[4][128];
  __shared__ float ssq[4][128];
  int tid = threadIdx.x;
  int w = tid >> 6, lane = tid & 63;
  int oct = lane >> 3, hh = lane & 7;
  int n = blockIdx.x*4 + w;
  bool active = (n < N);

  float acc[16];
  #pragma unroll
  for (int i = 0; i < 16; ++i) acc[i] = 0.f;
  float lsum = 0.f;

  if (active){
    uint4 q0 = qh4[(size_t)n*16 + hh*2];
    uint4 q1 = qh4[(size_t)n*16 + hh*2 + 1];
    unsigned qr[8] = {q0.x,q0.y,q0.z,q0.w, q1.x,q1.y,q1.z,q1.w};
    int beg = rp[n], end = rp[n+1];
    int t = beg + oct;
    bool vcur = (t < end);
    uint4 g0, g1, g2, g3;
    if (vcur){
      const uint4* base = kvh4 + (size_t)srcs[t]*32 + hh*4;
      g0 = base[0]; g1 = base[1]; g2 = base[2]; g3 = base[3];
    }
    while (vcur){
      int tn = t + 8;
      bool vn = (tn < end);
      int sn = vn ? srcs[tn] : 0;
      const uint4* nb = kvh4 + (size_t)sn*32 + hh*4;
      uint4 n0 = nb[0], n1 = nb[1], n2 = nb[2], n3 = nb[3];

      unsigned kr[8] = {g0.x,g0.y,g0.z,g0.w, g1.x,g1.y,g1.z,g1.w};
      float pd = 0.f;
      #pragma unroll
      for (int i = 0; i < 8; ++i) pd = fdot2u(kr[i], qr[i], pd);
      float e = __expf(pd * 0.25f);
      lsum += e;
      unsigned vr[8] = {g2.x,g2.y,g2.z,g2.w, g3.x,g3.y,g3.z,g3.w};
      #pragma unroll
      for (int i = 0; i < 8; ++i){
        float2 vf = __half22float2(*(__half2*)&vr[i]);
        acc[2*i]   += e*vf.x;
        acc[2*i+1] += e*vf.y;
      }
      g0 = n0; g1 = n1; g2 = n2; g3 = n3;
      t = tn; vcur = vn;
    }
  }

  #pragma unroll
  for (int mask = 8; mask <= 32; mask <<= 1){
    lsum += __shfl_xor(lsum, mask);
    #pragma unroll
    for (int i = 0; i < 16; ++i) acc[i] += __shfl_xor(acc[i], mask);
  }
  float inv = (lsum > 0.f) ? 1.f/lsum : 0.f;

  float out[16];
  #pragma unroll
  for (int i = 0; i < 16; ++i) out[i] = 0.f;
  if (active && oct == 0){
    uint4* hp = (uint4*)(h_u + (size_t)n*64 + hh*8);
    uint4 s0 = hp[0], s1 = hp[1];
    unsigned sr[8] = {s0.x,s0.y,s0.z,s0.w, s1.x,s1.y,s1.z,s1.w};
    #pragma unroll
    for (int i = 0; i < 8; ++i){
      float2 sk = __half22float2(*(__half2*)&sr[i]);
      out[2*i]   = fmaxf(acc[2*i]*inv   + sk.x, 0.f);
      out[2*i+1] = fmaxf(acc[2*i+1]*inv + sk.y, 0.f);
    }
    uint4 w0, w1;
    w0.x = h2bits(__floats2half2_rn(out[0], out[1]));
    w0.y = h2bits(__floats2half2_rn(out[2], out[3]));
    w0.z = h2bits(__floats2half2_rn(out[4], out[5]));
    w0.w = h2bits(__floats2half2_rn(out[6], out[7]));
    w1.x = h2bits(__floats2half2_rn(out[8], out[9]));
    w1.y = h2bits(__floats2half2_rn(out[10], out[11]));
    w1.z = h2bits(__floats2half2_rn(out[12], out[13]));
    w1.w = h2bits(__floats2half2_rn(out[14], out[15]));
    hp[0] = w0; hp[1] = w1;
  }
  if (oct == 0){
    #pragma unroll
    for (int j = 0; j < 16; ++j){
      int pidx = j*8 + hh;
      ssum[w][pidx] = out[j];
      ssq[w][pidx]  = out[j]*out[j];
    }
  }
  __syncthreads();
  float* prow = pr2 + (size_t)(layer & 1)*16384 + (size_t)(blockIdx.x & 63)*256;
  if (tid < 128){
    atomicAdd(&prow[tid], ssum[0][tid]+ssum[1][tid]+ssum[2][tid]+ssum[3][tid]);
  } else {
    int c = tid - 128;
    atomicAdd(&prow[tid], ssq[0][c]+ssq[1][c]+ssq[2][c]+ssq[3][c]);
  }
}

// ---------------- BN finalize v2: cooperative scl/bb in LDS + vectorized uint4 body ----------------
__global__ __launch_bounds__(256) void k_bnfin(
    const uint4* __restrict__ h4, uint4* __restrict__ x4,
    float* __restrict__ pr2, int layer,
    const float* __restrict__ gamma, const float* __restrict__ beta,
    int nchunk, int resid, float invN){
  __shared__ float sscl[128], sbb[128];
  int t = threadIdx.x;
  if (t < 128){
    int c = t;
    int p = ((c & 15) << 3) | (c >> 4);   // transposed position holding channel c
    const float* pb = pr2 + (size_t)(layer & 1)*16384;
    float s = 0.f, sq = 0.f;
    #pragma unroll 8
    for (int i = 0; i < 64; ++i){
      s  += pb[i*256 + p];
      sq += pb[i*256 + 128 + p];
    }
    float mu  = s * invN;
    float var = sq * invN - mu*mu;
    float scl = rsqrtf(var + 1e-5f) * gamma[c];
    sscl[c] = scl;
    sbb[c]  = beta[c] - mu*scl;
  }
  // zero the buffer the NEXT attn layer will accumulate into
  if (blockIdx.x < 64){
    pr2[(size_t)((layer + 1) & 1)*16384 + (size_t)blockIdx.x*256 + t] = 0.f;
  }
  __syncthreads();
  int stride = gridDim.x * 256;
  for (int ci = blockIdx.x*256 + t; ci < nchunk; ci += stride){
    int cb = (ci & 15) << 3;   // first of 8 channels in this chunk
    uint4 hv = h4[ci];
    unsigned hr[4] = {hv.x, hv.y, hv.z, hv.w};
    uint4 ov;
    unsigned* op = &ov.x;
    if (resid){
      uint4 xv = x4[ci];
      unsigned xr[4] = {xv.x, xv.y, xv.z, xv.w};
      #pragma unroll
      for (int j = 0; j < 4; ++j){
        float2 hf = __half22float2(*(__half2*)&hr[j]);
        float2 xf = __half22float2(*(__half2*)&xr[j]);
        float o0 = hf.x*sscl[cb+2*j]   + sbb[cb+2*j]   + xf.x;
        float o1 = hf.y*sscl[cb+2*j+1] + sbb[cb+2*j+1] + xf.y;
        op[j] = h2bits(__floats2half2_rn(o0, o1));
      }
    } else {
      #pragma unroll
      for (int j = 0; j < 4; ++j){
        float2 hf = __half22float2(*(__half2*)&hr[j]);
        float o0 = hf.x*sscl[cb+2*j]   + sbb[cb+2*j];
        float o1 = hf.y*sscl[cb+2*j+1] + sbb[cb+2*j+1];
        op[j] = h2bits(__floats2half2_rn(o0, o1));
      }
    }
    x4[ci] = ov;
  }
}

// ---------------- pool stage 1 (vectorized uint4, 4 chunks) ----------------
__global__ __launch_bounds__(256) void k_pool1(
    const uint4* __restrict__ x4, const int* __restrict__ gstart,
    float* __restrict__ pp, int N){
  __shared__ float sm[2048];
  int g = blockIdx.x, chunk = blockIdx.y;
  int t = threadIdx.x;
  int tcol = t & 15, trow = t >> 4;
  int start = gstart[g];
  int endr  = gstart[g+1];
  float facc[8];
  #pragma unroll
  for (int j = 0; j < 8; ++j) facc[j] = 0.f;
  for (int r = start + chunk*16 + trow; r < endr; r += 64){
    uint4 v = x4[(size_t)r*16 + tcol];
    unsigned vr[4] = {v.x, v.y, v.z, v.w};
    #pragma unroll
    for (int j = 0; j < 4; ++j){
      float2 f = __half22float2(*(__half2*)&vr[j]);
      facc[2*j]   += f.x;
      facc[2*j+1] += f.y;
    }
  }
  #pragma unroll
  for (int j = 0; j < 8; ++j) sm[t*8 + j] = facc[j];   // sm[trow*128 + c]
  __syncthreads();
  if (t < 128){
    float s = 0.f;
    #pragma unroll
    for (int r = 0; r < 16; ++r) s += sm[r*128 + t];
    pp[(size_t)(g*4 + chunk)*128 + t] = s;
  }
}

// ---------------- pool stage 2 ----------------
__global__ __launch_bounds__(128) void k_pool2(
    const float* __restrict__ pp, const int* __restrict__ gstart,
    const float* __restrict__ Wr, const float* __restrict__ br,
    float* __restrict__ out){
  __shared__ float sm[128];
  int g = blockIdx.x, c = threadIdx.x;
  float s = 0.f;
  #pragma unroll
  for (int j = 0; j < 4; ++j) s += pp[(size_t)(g*4 + j)*128 + c];
  int cnt = gstart[g+1] - gstart[g];
  float xm = s / fmaxf((float)cnt, 1.f);
  out[NGRAPH + g*HD + c] = xm;
  sm[c] = xm * Wr[c];
  __syncthreads();
  for (int off = 64; off > 0; off >>= 1){
    if (c < off) sm[c] += sm[c + off];
    __syncthreads();
  }
  if (c == 0) out[g] = sm[0] + br[0];
}

extern "C" void kernel_launch(void* const* d_in, const int* in_sizes, int n_in,
                              void* d_out, int out_size, void* d_ws, size_t ws_size,
                              hipStream_t stream){
  const float* X     = (const float*)d_in[0];
  const int*   ei    = (const int*)  d_in[1];
  const int*   batch = (const int*)  d_in[2];
  const float* Wq1 = (const float*)d_in[3];  const float* bq1 = (const float*)d_in[4];
  const float* Wk1 = (const float*)d_in[5];  const float* bk1 = (const float*)d_in[6];
  const float* Wv1 = (const float*)d_in[7];  const float* bv1 = (const float*)d_in[8];
  const float* Ws1 = (const float*)d_in[9];  const float* bs1 = (const float*)d_in[10];
  const float* Wq  = (const float*)d_in[11]; const float* bq  = (const float*)d_in[12];
  const float* Wk  = (const float*)d_in[13]; const float* bk  = (const float*)d_in[14];
  const float* Wv  = (const float*)d_in[15]; const float* bv  = (const float*)d_in[16];
  const float* Ws  = (const float*)d_in[17]; const float* bs  = (const float*)d_in[18];
  const float* bn_g= (const float*)d_in[19]; const float* bn_b= (const float*)d_in[20];
  const float* Wr  = (const float*)d_in[21]; const float* br  = (const float*)d_in[22];

  const int N = in_sizes[0];
  const int E = in_sizes[1] / 2;

  const int* src = ei;
  const int* dst = ei + E;

  char* p = (char*)d_ws;
  auto alloc = [&](size_t bytes) -> void* {
    void* r = (void*)p;
    p += (bytes + 255) & ~(size_t)255;
    return r;
  };
  int*   deg  = (int*)alloc((size_t)N * 4);           // zeroed
  float* pr2  = (float*)alloc(2 * 64 * 256 * 4);      // zeroed (both parity buffers)
  char* zero_end = p;
  int* rp     = (int*)alloc((size_t)(N + 1) * 4);
  int* bt     = (int*)alloc(256 * 4);
  int* gstart = (int*)alloc((NGRAPH + 1) * 4);
  int* epos   = (int*)alloc((size_t)E * 4);
  int* srcs   = (int*)alloc((size_t)E * 4);
  float* pp   = (float*)alloc((size_t)NGRAPH * 4 * 128 * 4);
  uint4* Wpack= (uint4*)alloc((size_t)16 * 2048 * 16);
  unsigned* qh_u  = (unsigned*)alloc((size_t)N * 64 * 4);
  unsigned* kvh_u = (unsigned*)alloc((size_t)N * 128 * 4);
  unsigned* h_u   = (unsigned*)alloc((size_t)N * 64 * 4);
  __half* x   = (__half*)alloc((size_t)N * HD * 2);

  hipMemsetAsync(deg, 0, (size_t)(zero_end - (char*)deg), stream);

  const int NB  = (N + 255) / 256;
  const int EB  = (E + 255) / 256;
  const int L1B = (N * 32 + 255) / 256;
  const int NBLK = (N + 3) / 4;
  const int NCH = N * 16;            // uint4 chunks in x/h
  const float invN = 1.f / (float)N;

  k_count_setup<<<EB + L1B + 129, 256, 0, stream>>>(
      dst, deg, epos, E, EB,
      X, Wq1,bq1, Wk1,bk1, Wv1,bv1, Ws1,bs1,
      Wq, Wk, Wv, Ws, batch, gstart, Wpack, qh_u, kvh_u, h_u, N, L1B);
  k_scan1  <<<NB, 256, 0, stream>>>(deg, rp, bt, N);
  k_scan3  <<<NB, 256, 0, stream>>>(rp, bt, N);
  k_scatter<<<EB, 256, 0, stream>>>(src, dst, rp, epos, srcs, E);

  // layer 1 (layer index 0)
  k_attn <<<NBLK, 256, 0, stream>>>((const uint4*)qh_u, (const uint4*)kvh_u, h_u, pr2, rp, srcs, N, 0);
  k_bnfin<<<512, 256, 0, stream>>>((const uint4*)h_u, (uint4*)x, pr2, 0, bn_g, bn_b, NCH, 0, invN);

  // layers 2..5 (layer index 1..4)
  for (int l = 0; l < 4; ++l){
    k_gemm<<<dim3((N + 255) / 256, 4), 256, 0, stream>>>(
        x, Wpack, bq + (size_t)l*HD, bk + (size_t)l*HD, bv + (size_t)l*HD, bs + (size_t)l*HD,
        qh_u, kvh_u, h_u, N, l);
    k_attn<<<NBLK, 256, 0, stream>>>((const uint4*)qh_u, (const uint4*)kvh_u, h_u, pr2, rp, srcs, N, l + 1);
    k_bnfin<<<512, 256, 0, stream>>>((const uint4*)h_u, (uint4*)x, pr2, l + 1,
                                     bn_g + (size_t)(l+1)*HD, bn_b + (size_t)(l+1)*HD, NCH, 1, invN);
  }

  // pool + head
  k_pool1<<<dim3(NGRAPH, 4), 256, 0, stream>>>((const uint4*)x, gstart, pp, N);
  k_pool2<<<NGRAPH, 128, 0, stream>>>(pp, gstart, Wr, br, (float*)d_out);
}